// Round 10
// baseline (608.234 us; speedup 1.0000x reference)
//
#include <hip/hip_runtime.h>
#include <hip/hip_bf16.h>
#include <math.h>

// GraphMAE: 3x GCNConv(relu) encoder -> 3-layer MLP decoder -> masked MSE.
// bf16 activation storage, f32 compute, MFMA bf16 matmuls.
// Round 10: CSR fill = fillm (each block serves ONLY the dst-partition of its
// physical XCD via HW_REG_XCC_ID; csr lines single-XCD -> coalesced in L2,
// written back once) + fillf safety net (places any edge fillm missed, via
// per-edge flags; correct under any block->XCD mapping).
// Outputs: d_out[0] = loss, d_out[1..N*128] = z (f32).

#define DD 128

typedef unsigned short ushort_t;
typedef unsigned int uint_t;
typedef __attribute__((ext_vector_type(8))) short short8;
typedef __attribute__((ext_vector_type(4))) float f32x4;

__device__ __forceinline__ ushort_t f2bf(float f) {
  union { float f; uint_t u; } v; v.f = f;
  uint_t r = v.u + 0x7fff + ((v.u >> 16) & 1);
  return (ushort_t)(r >> 16);
}
__device__ __forceinline__ float u2f(uint_t u) {
  union { uint_t u; float f; } v; v.u = u;
  return v.f;
}

// ---------------- dtype detection (edge_index: i64 vs i32; mask: i32 vs u8) ---
__global__ void detect_kernel(const void* edge, const void* mask,
                              long long E, int N, int* flags) {
  __shared__ int bad_e, bad_m;
  if (threadIdx.x == 0) { bad_e = 0; bad_m = 0; }
  __syncthreads();
  const long long* e64 = (const long long*)edge;
  long long step = E / 1024; if (step < 1) step = 1;
  for (int i = threadIdx.x; i < 1024; i += blockDim.x) {
    long long idx = (long long)i * step;
    if (idx < E) {
      long long v = e64[idx];
      if (v < 0 || v >= N) atomicAdd(&bad_e, 1);
    }
  }
  const int* m32 = (const int*)mask;
  int nw = N / 4;
  for (int i = threadIdx.x; i < nw; i += blockDim.x) {
    int v = m32[i];
    if (v != 0 && v != 1) atomicAdd(&bad_m, 1);
  }
  __syncthreads();
  if (threadIdx.x == 0) {
    flags[0] = (bad_e == 0) ? 1 : 0;
    flags[1] = (bad_m == 0) ? 1 : 0;
  }
}

__device__ __forceinline__ int load_mask(const void* p, int i, int is32) {
  if (is32) return ((const int*)p)[i];
  return (int)((const unsigned char*)p)[i];
}

// ---------------- edge convert to int32 + degree count (fused) --------------
__global__ void cvt_kernel(const void* edge, long long E, int* s32, int* d32,
                           int* deg, const int* flags) {
  int is64 = flags[0];
  long long i = blockIdx.x * (long long)blockDim.x + threadIdx.x;
  long long stride = (long long)gridDim.x * blockDim.x;
  for (; i < E; i += stride) {
    int s, d;
    if (is64) {
      s = (int)((const long long*)edge)[i];
      d = (int)((const long long*)edge)[E + i];
    } else {
      s = ((const int*)edge)[i];
      d = ((const int*)edge)[E + i];
    }
    s32[i] = s;
    d32[i] = d;
    atomicAdd(&deg[d], 1);
  }
}

__global__ void dinv_kernel(const int* deg, float* dinv, int N, int Npad) {
  int i = blockIdx.x * blockDim.x + threadIdx.x;
  if (i < Npad) dinv[i] = (i < N) ? rsqrtf((float)deg[i] + 1.0f) : 0.f;
}

// ---------------- exclusive scan (3-pass) ----------------
__global__ void scan1_kernel(const int* cnt, int* row_excl, int* blocksums, int N) {
  __shared__ int s[1024];
  int t = threadIdx.x, g = blockIdx.x * 1024 + t;
  int v = (g < N) ? cnt[g] : 0;
  s[t] = v;
  __syncthreads();
  for (int off = 1; off < 1024; off <<= 1) {
    int add = (t >= off) ? s[t - off] : 0;
    __syncthreads();
    s[t] += add;
    __syncthreads();
  }
  if (g < N) row_excl[g] = s[t] - v;
  if (t == 1023) blocksums[blockIdx.x] = s[1023];
}

__global__ void scan2_kernel(int* blocksums, int nb, int* row_ptr, int N) {
  if (threadIdx.x == 0 && blockIdx.x == 0) {
    int run = 0;
    for (int b = 0; b < nb; ++b) { int t = blocksums[b]; blocksums[b] = run; run += t; }
    row_ptr[N] = run;
  }
}

__global__ void scan3_kernel(int* row_ptr, const int* blocksums, int* cursor, int N) {
  int g = blockIdx.x * 1024 + threadIdx.x;
  if (g < N) {
    int v = row_ptr[g] + blocksums[blockIdx.x];
    row_ptr[g] = v;
    cursor[g] = v;
  }
}

// ---------------- CSR fill: physical-XCD-exclusive partitions ----------------
// Each block serves ONLY the dst-range partition matching its physical XCD id.
// All writers of a csr line are on one XCD -> L2 coalesces the 4B scatters,
// one writeback per line. Placed edges set eflag[i].
__global__ void fillm_kernel(const int* __restrict__ s32, const int* __restrict__ d32,
                             long long E, int* cursor, int* csr_src,
                             unsigned char* __restrict__ eflag, int N) {
  unsigned xcc;
  asm("s_getreg_b32 %0, hwreg(HW_REG_XCC_ID)" : "=s"(xcc));
  int part = (int)(xcc & 7u);
  int lo = (int)(((long long)N * part) >> 3);
  int hi = (int)(((long long)N * (part + 1)) >> 3);
  long long i = (long long)blockIdx.x * blockDim.x + threadIdx.x;
  long long stride = (long long)gridDim.x * blockDim.x;
  for (; i < E; i += stride) {
    int d = d32[i];
    if (d >= lo && d < hi) {
      int pos = atomicAdd(&cursor[d], 1);
      csr_src[pos] = s32[i];
      eflag[i] = 1;
    }
  }
}

// Safety net: place any edge fillm missed (normally none -> pure flag scan).
__global__ void fillf_kernel(const int* __restrict__ s32, const int* __restrict__ d32,
                             long long E, int* cursor, int* csr_src,
                             const unsigned char* __restrict__ eflag) {
  long long i = (long long)blockIdx.x * blockDim.x + threadIdx.x;
  long long stride = (long long)gridDim.x * blockDim.x;
  for (; i < E; i += stride) {
    if (!eflag[i]) {
      int pos = atomicAdd(&cursor[d32[i]], 1);
      csr_src[pos] = s32[i];
    }
  }
}

// ---------------- transpose+cast weights: W[k][n] f32 -> WT[n][k] bf16 ------
struct WPtrs { const float* w[6]; };
__global__ void transw_kernel(WPtrs p, ushort_t* wt) {
  int wi = blockIdx.x;
  const float* W = p.w[wi];
  ushort_t* dst = wt + wi * 16384;
  for (int i = threadIdx.x; i < 16384; i += blockDim.x) {
    int k = i >> 7, n = i & 127;
    dst[n * 128 + k] = f2bf(W[i]);
  }
}

// ---------------- mask compaction (order-free) ----------------
__global__ void compact_kernel(const void* mask, const int* flags, int N,
                               int* cnt, int* midx) {
  int i = blockIdx.x * blockDim.x + threadIdx.x;
  if (i < N && load_mask(mask, i, flags[1])) {
    int p = atomicAdd(cnt, 1);
    midx[p] = i;
  }
}

// ---------------- MFMA matmul: out[rows][128] = A[rows][128] @ W ------------
// A bf16 row-major OR f32 (Af32 path, converted in-register; rows >= nvalid
// read as zero). WT bf16 [n][k] pre-transposed, LDS-staged w/ XOR swizzle.
// gidx: logical row r reads A row gidx[r]. gM: device row limit (compact).
// scale: per-row output multiplier (dinv premult). xloss/lidx/accum: fused
// masked-MSE epilogue (no stores; block-reduced atomicAdd of sq-diff).
__launch_bounds__(256, 4)
__global__ void mm_kernel(const ushort_t* __restrict__ A, const float* __restrict__ Af32,
                          int nvalid, const ushort_t* __restrict__ WT,
                          const float* __restrict__ bias, ushort_t* __restrict__ outb,
                          float* __restrict__ outf, int do_relu, int nrows,
                          const int* __restrict__ gidx, const int* __restrict__ gM,
                          const float* __restrict__ scale,
                          const float* __restrict__ xloss, const int* __restrict__ lidx,
                          float* __restrict__ accum) {
  int limit = nrows;
  if (gM) limit = *gM;
  if ((long long)blockIdx.x * 64 >= limit) return;

  __shared__ __align__(16) char lds[32768];
  int tid = threadIdx.x;
  for (int cid = tid; cid < 2048; cid += 256) {
    int n = cid >> 4, kc = cid & 15;
    int dst = n * 256 + ((kc * 16) ^ ((n & 7) << 4));
    *(float4*)(lds + dst) = *(const float4*)(WT + n * 128 + kc * 8);
  }
  __syncthreads();

  int w = tid >> 6, l = tid & 63;
  long long R0 = (long long)blockIdx.x * 64 + w * 16;
  f32x4 acc[8];
#pragma unroll
  for (int c = 0; c < 8; ++c) acc[c] = (f32x4){0.f, 0.f, 0.f, 0.f};

  int r_log = (int)R0 + (l & 15);
  long long r_phys = r_log;
  if (gidx) r_phys = (r_log < limit) ? (long long)gidx[r_log] : 0;
#pragma unroll
  for (int ks = 0; ks < 4; ++ks) {
    short8 a;
    if (Af32) {
      if (r_log < nvalid) {
        const float* ar = Af32 + r_phys * 128 + ks * 32 + ((l >> 4) << 3);
        float4 f0 = *(const float4*)ar;
        float4 f1 = *(const float4*)(ar + 4);
        a[0] = (short)f2bf(f0.x); a[1] = (short)f2bf(f0.y);
        a[2] = (short)f2bf(f0.z); a[3] = (short)f2bf(f0.w);
        a[4] = (short)f2bf(f1.x); a[5] = (short)f2bf(f1.y);
        a[6] = (short)f2bf(f1.z); a[7] = (short)f2bf(f1.w);
      } else {
#pragma unroll
        for (int j = 0; j < 8; ++j) a[j] = 0;
      }
    } else {
      a = *(const short8*)(A + r_phys * 128 + ks * 32 + ((l >> 4) << 3));
    }
#pragma unroll
    for (int c = 0; c < 8; ++c) {
      int nn = c * 16 + (l & 15);
      int kb = ks * 64 + ((l >> 4) << 4);
      short8 b = *(const short8*)(lds + nn * 256 + (kb ^ ((nn & 7) << 4)));
      acc[c] = __builtin_amdgcn_mfma_f32_16x16x32_bf16(a, b, acc[c], 0, 0, 0);
    }
  }

  int store_limit = gM ? limit : nrows;
  long long gr0 = R0 + ((l >> 4) << 2);
  float sc[4] = {1.f, 1.f, 1.f, 1.f};
  if (scale) {
#pragma unroll
    for (int r = 0; r < 4; ++r)
      sc[r] = (gr0 + r < store_limit) ? scale[gr0 + r] : 0.f;
  }
  float local_sq = 0.f;
#pragma unroll
  for (int c = 0; c < 8; ++c) {
    int col = c * 16 + (l & 15);
    float bia = bias ? bias[col] : 0.f;
#pragma unroll
    for (int r = 0; r < 4; ++r) {
      if (gr0 + r < store_limit) {
        float v = acc[c][r] * sc[r] + bia;
        if (do_relu) v = fmaxf(v, 0.f);
        long long idx = (gr0 + r) * 128 + col;
        if (outb) outb[idx] = f2bf(v);
        if (outf) outf[idx] = v;
        if (xloss) {
          int orow = lidx[gr0 + r];
          float d = v - xloss[(size_t)orow * 128 + col];
          local_sq += d * d;
        }
      }
    }
  }
  if (accum) {
    float s = local_sq;
    for (int off2 = 32; off2; off2 >>= 1) s += __shfl_down(s, off2);
    __syncthreads();
    float* red = (float*)lds;
    if (l == 0) red[w] = s;
    __syncthreads();
    if (tid == 0) atomicAdd(accum, red[0] + red[1] + red[2] + red[3]);
  }
}

// ---------------- GCN aggregation (wave/node; ht rows dinv-premultiplied) ----
// out[v] = relu(dv*(sum_{edges} ht[s] + ht[v]) + b); 8 gathers in flight.
__global__ void agg_kernel(const ushort_t* __restrict__ ht, const float* __restrict__ dinv,
                           const int* __restrict__ rp, const int* __restrict__ csr,
                           const float* __restrict__ bias, ushort_t* __restrict__ outb,
                           float* __restrict__ zout, int N) {
  int v = blockIdx.x * 4 + (threadIdx.x >> 6);
  if (v >= N) return;
  int l = threadIdx.x & 63;
  int off = l * 2;
  int e0 = __builtin_amdgcn_readfirstlane(rp[v]);
  int e1 = __builtin_amdgcn_readfirstlane(rp[v + 1]);

  float ax[8], ay[8];
#pragma unroll
  for (int j = 0; j < 8; ++j) { ax[j] = 0.f; ay[j] = 0.f; }

  int deg = e1 - e0;
  int nfull = deg & ~7;
  int efull = e0 + nfull;
  for (int e = e0; e < efull; e += 8) {
#pragma unroll
    for (int j = 0; j < 8; ++j) {
      int s = __builtin_amdgcn_readfirstlane(csr[e + j]);
      uint_t hv = *(const uint_t*)(ht + (size_t)s * 128 + off);
      ax[j] += u2f(hv << 16);
      ay[j] += u2f(hv & 0xffff0000u);
    }
  }
  if (efull < e1) {
#pragma unroll
    for (int j = 0; j < 8; ++j) {
      int idx = efull + j;
      int cs = __builtin_amdgcn_readfirstlane(csr[idx]);  // csr has +16 slack
      int s = (idx < e1) ? cs : N;                        // row N is all-zero
      uint_t hv = *(const uint_t*)(ht + (size_t)s * 128 + off);
      ax[j] += u2f(hv << 16);
      ay[j] += u2f(hv & 0xffff0000u);
    }
  }

  float dv = dinv[v];
  uint_t sv = *(const uint_t*)(ht + (size_t)v * 128 + off);
  float axs = ((ax[0] + ax[1]) + (ax[2] + ax[3])) + ((ax[4] + ax[5]) + (ax[6] + ax[7]));
  float ays = ((ay[0] + ay[1]) + (ay[2] + ay[3])) + ((ay[4] + ay[5]) + (ay[6] + ay[7]));
  axs += u2f(sv << 16);
  ays += u2f(sv & 0xffff0000u);
  float vx = fmaxf(dv * axs + bias[off], 0.f);
  float vy = fmaxf(dv * ays + bias[off + 1], 0.f);
  uint_t packed = (uint_t)f2bf(vx) | ((uint_t)f2bf(vy) << 16);
  *(uint_t*)(outb + (size_t)v * 128 + off) = packed;
  if (zout) {
    *(float2*)(zout + (size_t)v * 128 + off) = make_float2(vx, vy);
  }
}

__global__ void finalize_kernel(const float* accum, const int* cnt, float* out) {
  float denom = fmaxf((float)*cnt, 1.0f) * 128.0f;
  out[0] = *accum / denom;
}

// ---------------- launch ----------------
extern "C" void kernel_launch(void* const* d_in, const int* in_sizes, int n_in,
                              void* d_out, int out_size, void* d_ws, size_t ws_size,
                              hipStream_t stream) {
  const float* x  = (const float*)d_in[0];
  const void* edge = d_in[1];
  const void* mask = d_in[2];
  const float* W1 = (const float*)d_in[3];
  const float* b1 = (const float*)d_in[4];
  const float* W2 = (const float*)d_in[5];
  const float* b2 = (const float*)d_in[6];
  const float* W3 = (const float*)d_in[7];
  const float* b3 = (const float*)d_in[8];
  const float* D1 = (const float*)d_in[9];
  const float* db1 = (const float*)d_in[10];
  const float* D2 = (const float*)d_in[11];
  const float* db2 = (const float*)d_in[12];
  const float* D3 = (const float*)d_in[13];
  const float* db3 = (const float*)d_in[14];

  int N = in_sizes[0] / DD;
  long long E = in_sizes[1] / 2;
  long long Npad = ((long long)N + 63) & ~63LL;

  char* ws = (char*)d_ws;
  size_t p = 0;
  auto alloc = [&](size_t bytes) {
    size_t o = p;
    p = (p + bytes + 255) & ~(size_t)255;
    return o;
  };
  int* flags   = (int*)(ws + alloc(8));
  float* accum = (float*)(ws + alloc(4));
  int* mcnt    = (int*)(ws + alloc(4));
  int* deg     = (int*)(ws + alloc(sizeof(int) * N));
  float* dinv  = (float*)(ws + alloc(sizeof(float) * Npad));
  int* row_ptr = (int*)(ws + alloc(sizeof(int) * (N + 1)));
  int* cursor  = (int*)(ws + alloc(sizeof(int) * N));
  int* bsums   = (int*)(ws + alloc(sizeof(int) * 1024));
  int* midx    = (int*)(ws + alloc(sizeof(int) * N));
  int* s32     = (int*)(ws + alloc(sizeof(int) * E));
  int* d32     = (int*)(ws + alloc(sizeof(int) * E));
  int* csr     = (int*)(ws + alloc(sizeof(int) * (E + 16)));
  unsigned char* eflag = (unsigned char*)(ws + alloc((size_t)E));
  ushort_t* wt = (ushort_t*)(ws + alloc(sizeof(ushort_t) * 6 * 128 * 128));
  ushort_t* hb = (ushort_t*)(ws + alloc(sizeof(ushort_t) * (size_t)Npad * DD));
  ushort_t* gb = (ushort_t*)(ws + alloc(sizeof(ushort_t) * (size_t)Npad * DD));

  hipMemsetAsync(deg, 0, sizeof(int) * N, stream);
  hipMemsetAsync(accum, 0, 4, stream);
  hipMemsetAsync(mcnt, 0, 4, stream);
  hipMemsetAsync(eflag, 0, (size_t)E, stream);
  // zero pad rows (N..Npad) of both activation buffers: row N is the safe
  // zero gather target for agg tails, and keeps NaN garbage out of pads.
  size_t padoff = (size_t)N * DD, padbytes = (size_t)(Npad - N) * DD * sizeof(ushort_t);
  hipMemsetAsync(hb + padoff, 0, padbytes, stream);
  hipMemsetAsync(gb + padoff, 0, padbytes, stream);

  // graph prep
  detect_kernel<<<1, 256, 0, stream>>>(edge, mask, E, N, flags);
  cvt_kernel<<<1024, 256, 0, stream>>>(edge, E, s32, d32, deg, flags);
  dinv_kernel<<<(int)((Npad + 255) / 256), 256, 0, stream>>>(deg, dinv, N, (int)Npad);
  int nb = (N + 1023) / 1024;
  scan1_kernel<<<nb, 1024, 0, stream>>>(deg, row_ptr, bsums, N);
  scan2_kernel<<<1, 1, 0, stream>>>(bsums, nb, row_ptr, N);
  scan3_kernel<<<nb, 1024, 0, stream>>>(row_ptr, bsums, cursor, N);
  fillm_kernel<<<4096, 256, 0, stream>>>(s32, d32, E, cursor, csr, eflag, N);
  fillf_kernel<<<2048, 256, 0, stream>>>(s32, d32, E, cursor, csr, eflag);
  compact_kernel<<<(N + 255) / 256, 256, 0, stream>>>(mask, flags, N, mcnt, midx);

  // weight prep
  WPtrs wp;
  wp.w[0] = W1; wp.w[1] = W2; wp.w[2] = W3;
  wp.w[3] = D1; wp.w[4] = D2; wp.w[5] = D3;
  transw_kernel<<<6, 256, 0, stream>>>(wp, wt);

  float* zout = (float*)d_out + 1;
  int mmb = (int)(Npad / 64);
  int aggb = (N + 3) / 4;

  // encoder (mm stores ht = dinv * (A@W) in bf16; mm1 reads f32 x directly)
  mm_kernel<<<mmb, 256, 0, stream>>>(nullptr, x, N, wt + 0 * 16384, nullptr, hb,
                                     nullptr, 0, (int)Npad, nullptr, nullptr, dinv,
                                     nullptr, nullptr, nullptr);
  agg_kernel<<<aggb, 256, 0, stream>>>(hb, dinv, row_ptr, csr, b1, gb, nullptr, N);
  mm_kernel<<<mmb, 256, 0, stream>>>(gb, nullptr, 0, wt + 1 * 16384, nullptr, hb,
                                     nullptr, 0, (int)Npad, nullptr, nullptr, dinv,
                                     nullptr, nullptr, nullptr);
  agg_kernel<<<aggb, 256, 0, stream>>>(hb, dinv, row_ptr, csr, b2, gb, nullptr, N);
  mm_kernel<<<mmb, 256, 0, stream>>>(gb, nullptr, 0, wt + 2 * 16384, nullptr, hb,
                                     nullptr, 0, (int)Npad, nullptr, nullptr, dinv,
                                     nullptr, nullptr, nullptr);
  agg_kernel<<<aggb, 256, 0, stream>>>(hb, dinv, row_ptr, csr, b3, gb, zout, N);

  // decoder on compact masked rows (d1 gathers z rows via midx; d3 fuses loss)
  mm_kernel<<<mmb, 256, 0, stream>>>(gb, nullptr, 0, wt + 3 * 16384, db1, hb,
                                     nullptr, 1, (int)Npad, midx, mcnt, nullptr,
                                     nullptr, nullptr, nullptr);
  mm_kernel<<<mmb, 256, 0, stream>>>(hb, nullptr, 0, wt + 4 * 16384, db2, gb,
                                     nullptr, 1, (int)Npad, nullptr, mcnt, nullptr,
                                     nullptr, nullptr, nullptr);
  mm_kernel<<<mmb, 256, 0, stream>>>(gb, nullptr, 0, wt + 5 * 16384, db3, nullptr,
                                     nullptr, 0, (int)Npad, nullptr, mcnt, nullptr,
                                     x, midx, accum);

  finalize_kernel<<<1, 1, 0, stream>>>(accum, mcnt, (float*)d_out);
}

// Round 11
// 577.498 us; speedup vs baseline: 1.0532x; 1.0532x over previous
//
#include <hip/hip_runtime.h>
#include <hip/hip_bf16.h>
#include <math.h>

// GraphMAE: 3x GCNConv(relu) encoder -> 3-layer MLP decoder -> masked MSE.
// bf16 activation storage, f32 compute, MFMA bf16 matmuls.
// Round 11: fill reverted to fillp@4096 (round-9 best; XCC_ID binding failed,
// CSR scatter write floor accepted as structural). mm tile 64->128 rows/block
// (halved weight-staging traffic + prologue overhead, 64 MFMA/wave).
// Outputs: d_out[0] = loss, d_out[1..N*128] = z (f32).

#define DD 128

typedef unsigned short ushort_t;
typedef unsigned int uint_t;
typedef __attribute__((ext_vector_type(8))) short short8;
typedef __attribute__((ext_vector_type(4))) float f32x4;

__device__ __forceinline__ ushort_t f2bf(float f) {
  union { float f; uint_t u; } v; v.f = f;
  uint_t r = v.u + 0x7fff + ((v.u >> 16) & 1);
  return (ushort_t)(r >> 16);
}
__device__ __forceinline__ float u2f(uint_t u) {
  union { uint_t u; float f; } v; v.u = u;
  return v.f;
}

// ---------------- dtype detection (edge_index: i64 vs i32; mask: i32 vs u8) ---
__global__ void detect_kernel(const void* edge, const void* mask,
                              long long E, int N, int* flags) {
  __shared__ int bad_e, bad_m;
  if (threadIdx.x == 0) { bad_e = 0; bad_m = 0; }
  __syncthreads();
  const long long* e64 = (const long long*)edge;
  long long step = E / 1024; if (step < 1) step = 1;
  for (int i = threadIdx.x; i < 1024; i += blockDim.x) {
    long long idx = (long long)i * step;
    if (idx < E) {
      long long v = e64[idx];
      if (v < 0 || v >= N) atomicAdd(&bad_e, 1);
    }
  }
  const int* m32 = (const int*)mask;
  int nw = N / 4;
  for (int i = threadIdx.x; i < nw; i += blockDim.x) {
    int v = m32[i];
    if (v != 0 && v != 1) atomicAdd(&bad_m, 1);
  }
  __syncthreads();
  if (threadIdx.x == 0) {
    flags[0] = (bad_e == 0) ? 1 : 0;
    flags[1] = (bad_m == 0) ? 1 : 0;
  }
}

__device__ __forceinline__ int load_mask(const void* p, int i, int is32) {
  if (is32) return ((const int*)p)[i];
  return (int)((const unsigned char*)p)[i];
}

// ---------------- edge convert to int32 + degree count (fused) --------------
__global__ void cvt_kernel(const void* edge, long long E, int* s32, int* d32,
                           int* deg, const int* flags) {
  int is64 = flags[0];
  long long i = blockIdx.x * (long long)blockDim.x + threadIdx.x;
  long long stride = (long long)gridDim.x * blockDim.x;
  for (; i < E; i += stride) {
    int s, d;
    if (is64) {
      s = (int)((const long long*)edge)[i];
      d = (int)((const long long*)edge)[E + i];
    } else {
      s = ((const int*)edge)[i];
      d = ((const int*)edge)[E + i];
    }
    s32[i] = s;
    d32[i] = d;
    atomicAdd(&deg[d], 1);
  }
}

__global__ void dinv_kernel(const int* deg, float* dinv, int N, int Npad) {
  int i = blockIdx.x * blockDim.x + threadIdx.x;
  if (i < Npad) dinv[i] = (i < N) ? rsqrtf((float)deg[i] + 1.0f) : 0.f;
}

// ---------------- exclusive scan (3-pass) ----------------
__global__ void scan1_kernel(const int* cnt, int* row_excl, int* blocksums, int N) {
  __shared__ int s[1024];
  int t = threadIdx.x, g = blockIdx.x * 1024 + t;
  int v = (g < N) ? cnt[g] : 0;
  s[t] = v;
  __syncthreads();
  for (int off = 1; off < 1024; off <<= 1) {
    int add = (t >= off) ? s[t - off] : 0;
    __syncthreads();
    s[t] += add;
    __syncthreads();
  }
  if (g < N) row_excl[g] = s[t] - v;
  if (t == 1023) blocksums[blockIdx.x] = s[1023];
}

__global__ void scan2_kernel(int* blocksums, int nb, int* row_ptr, int N) {
  if (threadIdx.x == 0 && blockIdx.x == 0) {
    int run = 0;
    for (int b = 0; b < nb; ++b) { int t = blocksums[b]; blocksums[b] = run; run += t; }
    row_ptr[N] = run;
  }
}

__global__ void scan3_kernel(int* row_ptr, const int* blocksums, int* cursor, int N) {
  int g = blockIdx.x * 1024 + threadIdx.x;
  if (g < N) {
    int v = row_ptr[g] + blocksums[blockIdx.x];
    row_ptr[g] = v;
    cursor[g] = v;
  }
}

// ---------------- CSR fill, partitioned by dst range, int32 streams ---------
__global__ void fillp_kernel(const int* __restrict__ s32, const int* __restrict__ d32,
                             long long E, int* cursor, int* csr_src, int N) {
  int part = blockIdx.x & 7;
  int lo = (int)(((long long)N * part) >> 3);
  int hi = (int)(((long long)N * (part + 1)) >> 3);
  long long i = (long long)(blockIdx.x >> 3) * blockDim.x + threadIdx.x;
  long long stride = (long long)(gridDim.x >> 3) * blockDim.x;
  for (; i < E; i += stride) {
    int d = d32[i];
    if (d >= lo && d < hi) {
      int s = s32[i];
      int pos = atomicAdd(&cursor[d], 1);
      csr_src[pos] = s;
    }
  }
}

// ---------------- transpose+cast weights: W[k][n] f32 -> WT[n][k] bf16 ------
struct WPtrs { const float* w[6]; };
__global__ void transw_kernel(WPtrs p, ushort_t* wt) {
  int wi = blockIdx.x;
  const float* W = p.w[wi];
  ushort_t* dst = wt + wi * 16384;
  for (int i = threadIdx.x; i < 16384; i += blockDim.x) {
    int k = i >> 7, n = i & 127;
    dst[n * 128 + k] = f2bf(W[i]);
  }
}

// ---------------- mask compaction (order-free) ----------------
__global__ void compact_kernel(const void* mask, const int* flags, int N,
                               int* cnt, int* midx) {
  int i = blockIdx.x * blockDim.x + threadIdx.x;
  if (i < N && load_mask(mask, i, flags[1])) {
    int p = atomicAdd(cnt, 1);
    midx[p] = i;
  }
}

// ---------------- MFMA matmul: out[rows][128] = A[rows][128] @ W ------------
// 128 rows/block (4 waves x 32 rows = 2 row-tiles of 16). A bf16 row-major OR
// f32 (Af32 path, in-register cast; rows >= nvalid read zero). WT bf16 [n][k]
// pre-transposed, LDS-staged w/ XOR swizzle. gidx: row gather. gM: device row
// limit (compact passes). scale: per-row output multiplier (dinv premult).
// xloss/lidx/accum: fused masked-MSE epilogue.
__launch_bounds__(256, 4)
__global__ void mm_kernel(const ushort_t* __restrict__ A, const float* __restrict__ Af32,
                          int nvalid, const ushort_t* __restrict__ WT,
                          const float* __restrict__ bias, ushort_t* __restrict__ outb,
                          float* __restrict__ outf, int do_relu, int nrows,
                          const int* __restrict__ gidx, const int* __restrict__ gM,
                          const float* __restrict__ scale,
                          const float* __restrict__ xloss, const int* __restrict__ lidx,
                          float* __restrict__ accum) {
  int limit = nrows;
  if (gM) limit = *gM;
  if ((long long)blockIdx.x * 128 >= limit) return;

  __shared__ __align__(16) char lds[32768];
  int tid = threadIdx.x;
  for (int cid = tid; cid < 2048; cid += 256) {
    int n = cid >> 4, kc = cid & 15;
    int dst = n * 256 + ((kc * 16) ^ ((n & 7) << 4));
    *(float4*)(lds + dst) = *(const float4*)(WT + n * 128 + kc * 8);
  }
  __syncthreads();

  int w = tid >> 6, l = tid & 63;
  long long R0 = (long long)blockIdx.x * 128 + w * 32;
  f32x4 acc[2][8];
#pragma unroll
  for (int g = 0; g < 2; ++g)
#pragma unroll
    for (int c = 0; c < 8; ++c) acc[g][c] = (f32x4){0.f, 0.f, 0.f, 0.f};

  int r_log[2];
  long long r_phys[2];
#pragma unroll
  for (int g = 0; g < 2; ++g) {
    r_log[g] = (int)R0 + g * 16 + (l & 15);
    r_phys[g] = r_log[g];
    if (gidx) r_phys[g] = (r_log[g] < limit) ? (long long)gidx[r_log[g]] : 0;
  }

#pragma unroll
  for (int ks = 0; ks < 4; ++ks) {
    short8 a[2];
#pragma unroll
    for (int g = 0; g < 2; ++g) {
      if (Af32) {
        if (r_log[g] < nvalid) {
          const float* ar = Af32 + r_phys[g] * 128 + ks * 32 + ((l >> 4) << 3);
          float4 f0 = *(const float4*)ar;
          float4 f1 = *(const float4*)(ar + 4);
          a[g][0] = (short)f2bf(f0.x); a[g][1] = (short)f2bf(f0.y);
          a[g][2] = (short)f2bf(f0.z); a[g][3] = (short)f2bf(f0.w);
          a[g][4] = (short)f2bf(f1.x); a[g][5] = (short)f2bf(f1.y);
          a[g][6] = (short)f2bf(f1.z); a[g][7] = (short)f2bf(f1.w);
        } else {
#pragma unroll
          for (int j = 0; j < 8; ++j) a[g][j] = 0;
        }
      } else {
        a[g] = *(const short8*)(A + r_phys[g] * 128 + ks * 32 + ((l >> 4) << 3));
      }
    }
#pragma unroll
    for (int c = 0; c < 8; ++c) {
      int nn = c * 16 + (l & 15);
      int kb = ks * 64 + ((l >> 4) << 4);
      short8 b = *(const short8*)(lds + nn * 256 + (kb ^ ((nn & 7) << 4)));
      acc[0][c] = __builtin_amdgcn_mfma_f32_16x16x32_bf16(a[0], b, acc[0][c], 0, 0, 0);
      acc[1][c] = __builtin_amdgcn_mfma_f32_16x16x32_bf16(a[1], b, acc[1][c], 0, 0, 0);
    }
  }

  int store_limit = gM ? limit : nrows;
  float local_sq = 0.f;
#pragma unroll
  for (int g = 0; g < 2; ++g) {
    long long gr0 = R0 + g * 16 + ((l >> 4) << 2);
    float sc[4] = {1.f, 1.f, 1.f, 1.f};
    if (scale) {
#pragma unroll
      for (int r = 0; r < 4; ++r)
        sc[r] = (gr0 + r < store_limit) ? scale[gr0 + r] : 0.f;
    }
#pragma unroll
    for (int c = 0; c < 8; ++c) {
      int col = c * 16 + (l & 15);
      float bia = bias ? bias[col] : 0.f;
#pragma unroll
      for (int r = 0; r < 4; ++r) {
        if (gr0 + r < store_limit) {
          float v = acc[g][c][r] * sc[r] + bia;
          if (do_relu) v = fmaxf(v, 0.f);
          long long idx = (gr0 + r) * 128 + col;
          if (outb) outb[idx] = f2bf(v);
          if (outf) outf[idx] = v;
          if (xloss) {
            int orow = lidx[gr0 + r];
            float d = v - xloss[(size_t)orow * 128 + col];
            local_sq += d * d;
          }
        }
      }
    }
  }
  if (accum) {
    float s = local_sq;
    for (int off2 = 32; off2; off2 >>= 1) s += __shfl_down(s, off2);
    __syncthreads();
    float* red = (float*)lds;
    if (l == 0) red[w] = s;
    __syncthreads();
    if (tid == 0) atomicAdd(accum, red[0] + red[1] + red[2] + red[3]);
  }
}

// ---------------- GCN aggregation (wave/node; ht rows dinv-premultiplied) ----
// out[v] = relu(dv*(sum_{edges} ht[s] + ht[v]) + b); 8 gathers in flight.
__global__ void agg_kernel(const ushort_t* __restrict__ ht, const float* __restrict__ dinv,
                           const int* __restrict__ rp, const int* __restrict__ csr,
                           const float* __restrict__ bias, ushort_t* __restrict__ outb,
                           float* __restrict__ zout, int N) {
  int v = blockIdx.x * 4 + (threadIdx.x >> 6);
  if (v >= N) return;
  int l = threadIdx.x & 63;
  int off = l * 2;
  int e0 = __builtin_amdgcn_readfirstlane(rp[v]);
  int e1 = __builtin_amdgcn_readfirstlane(rp[v + 1]);

  float ax[8], ay[8];
#pragma unroll
  for (int j = 0; j < 8; ++j) { ax[j] = 0.f; ay[j] = 0.f; }

  int deg = e1 - e0;
  int nfull = deg & ~7;
  int efull = e0 + nfull;
  for (int e = e0; e < efull; e += 8) {
#pragma unroll
    for (int j = 0; j < 8; ++j) {
      int s = __builtin_amdgcn_readfirstlane(csr[e + j]);
      uint_t hv = *(const uint_t*)(ht + (size_t)s * 128 + off);
      ax[j] += u2f(hv << 16);
      ay[j] += u2f(hv & 0xffff0000u);
    }
  }
  if (efull < e1) {
#pragma unroll
    for (int j = 0; j < 8; ++j) {
      int idx = efull + j;
      int cs = __builtin_amdgcn_readfirstlane(csr[idx]);  // csr has +16 slack
      int s = (idx < e1) ? cs : N;                        // row N is all-zero
      uint_t hv = *(const uint_t*)(ht + (size_t)s * 128 + off);
      ax[j] += u2f(hv << 16);
      ay[j] += u2f(hv & 0xffff0000u);
    }
  }

  float dv = dinv[v];
  uint_t sv = *(const uint_t*)(ht + (size_t)v * 128 + off);
  float axs = ((ax[0] + ax[1]) + (ax[2] + ax[3])) + ((ax[4] + ax[5]) + (ax[6] + ax[7]));
  float ays = ((ay[0] + ay[1]) + (ay[2] + ay[3])) + ((ay[4] + ay[5]) + (ay[6] + ay[7]));
  axs += u2f(sv << 16);
  ays += u2f(sv & 0xffff0000u);
  float vx = fmaxf(dv * axs + bias[off], 0.f);
  float vy = fmaxf(dv * ays + bias[off + 1], 0.f);
  uint_t packed = (uint_t)f2bf(vx) | ((uint_t)f2bf(vy) << 16);
  *(uint_t*)(outb + (size_t)v * 128 + off) = packed;
  if (zout) {
    *(float2*)(zout + (size_t)v * 128 + off) = make_float2(vx, vy);
  }
}

__global__ void finalize_kernel(const float* accum, const int* cnt, float* out) {
  float denom = fmaxf((float)*cnt, 1.0f) * 128.0f;
  out[0] = *accum / denom;
}

// ---------------- launch ----------------
extern "C" void kernel_launch(void* const* d_in, const int* in_sizes, int n_in,
                              void* d_out, int out_size, void* d_ws, size_t ws_size,
                              hipStream_t stream) {
  const float* x  = (const float*)d_in[0];
  const void* edge = d_in[1];
  const void* mask = d_in[2];
  const float* W1 = (const float*)d_in[3];
  const float* b1 = (const float*)d_in[4];
  const float* W2 = (const float*)d_in[5];
  const float* b2 = (const float*)d_in[6];
  const float* W3 = (const float*)d_in[7];
  const float* b3 = (const float*)d_in[8];
  const float* D1 = (const float*)d_in[9];
  const float* db1 = (const float*)d_in[10];
  const float* D2 = (const float*)d_in[11];
  const float* db2 = (const float*)d_in[12];
  const float* D3 = (const float*)d_in[13];
  const float* db3 = (const float*)d_in[14];

  int N = in_sizes[0] / DD;
  long long E = in_sizes[1] / 2;
  long long Npad = ((long long)N + 127) & ~127LL;

  char* ws = (char*)d_ws;
  size_t p = 0;
  auto alloc = [&](size_t bytes) {
    size_t o = p;
    p = (p + bytes + 255) & ~(size_t)255;
    return o;
  };
  int* flags   = (int*)(ws + alloc(8));
  float* accum = (float*)(ws + alloc(4));
  int* mcnt    = (int*)(ws + alloc(4));
  int* deg     = (int*)(ws + alloc(sizeof(int) * N));
  float* dinv  = (float*)(ws + alloc(sizeof(float) * Npad));
  int* row_ptr = (int*)(ws + alloc(sizeof(int) * (N + 1)));
  int* cursor  = (int*)(ws + alloc(sizeof(int) * N));
  int* bsums   = (int*)(ws + alloc(sizeof(int) * 1024));
  int* midx    = (int*)(ws + alloc(sizeof(int) * N));
  int* s32     = (int*)(ws + alloc(sizeof(int) * E));
  int* d32     = (int*)(ws + alloc(sizeof(int) * E));
  int* csr     = (int*)(ws + alloc(sizeof(int) * (E + 16)));
  ushort_t* wt = (ushort_t*)(ws + alloc(sizeof(ushort_t) * 6 * 128 * 128));
  ushort_t* hb = (ushort_t*)(ws + alloc(sizeof(ushort_t) * (size_t)Npad * DD));
  ushort_t* gb = (ushort_t*)(ws + alloc(sizeof(ushort_t) * (size_t)Npad * DD));

  hipMemsetAsync(deg, 0, sizeof(int) * N, stream);
  hipMemsetAsync(accum, 0, 4, stream);
  hipMemsetAsync(mcnt, 0, 4, stream);
  // zero pad rows (N..Npad): row N is the agg-tail zero gather target.
  size_t padoff = (size_t)N * DD, padbytes = (size_t)(Npad - N) * DD * sizeof(ushort_t);
  hipMemsetAsync(hb + padoff, 0, padbytes, stream);
  hipMemsetAsync(gb + padoff, 0, padbytes, stream);

  // graph prep
  detect_kernel<<<1, 256, 0, stream>>>(edge, mask, E, N, flags);
  cvt_kernel<<<1024, 256, 0, stream>>>(edge, E, s32, d32, deg, flags);
  dinv_kernel<<<(int)((Npad + 255) / 256), 256, 0, stream>>>(deg, dinv, N, (int)Npad);
  int nb = (N + 1023) / 1024;
  scan1_kernel<<<nb, 1024, 0, stream>>>(deg, row_ptr, bsums, N);
  scan2_kernel<<<1, 1, 0, stream>>>(bsums, nb, row_ptr, N);
  scan3_kernel<<<nb, 1024, 0, stream>>>(row_ptr, bsums, cursor, N);
  fillp_kernel<<<4096, 256, 0, stream>>>(s32, d32, E, cursor, csr, N);
  compact_kernel<<<(N + 255) / 256, 256, 0, stream>>>(mask, flags, N, mcnt, midx);

  // weight prep
  WPtrs wp;
  wp.w[0] = W1; wp.w[1] = W2; wp.w[2] = W3;
  wp.w[3] = D1; wp.w[4] = D2; wp.w[5] = D3;
  transw_kernel<<<6, 256, 0, stream>>>(wp, wt);

  float* zout = (float*)d_out + 1;
  int mmb = (int)(Npad / 128);
  int aggb = (N + 3) / 4;

  // encoder (mm stores ht = dinv * (A@W) in bf16; mm1 reads f32 x directly)
  mm_kernel<<<mmb, 256, 0, stream>>>(nullptr, x, N, wt + 0 * 16384, nullptr, hb,
                                     nullptr, 0, (int)Npad, nullptr, nullptr, dinv,
                                     nullptr, nullptr, nullptr);
  agg_kernel<<<aggb, 256, 0, stream>>>(hb, dinv, row_ptr, csr, b1, gb, nullptr, N);
  mm_kernel<<<mmb, 256, 0, stream>>>(gb, nullptr, 0, wt + 1 * 16384, nullptr, hb,
                                     nullptr, 0, (int)Npad, nullptr, nullptr, dinv,
                                     nullptr, nullptr, nullptr);
  agg_kernel<<<aggb, 256, 0, stream>>>(hb, dinv, row_ptr, csr, b2, gb, nullptr, N);
  mm_kernel<<<mmb, 256, 0, stream>>>(gb, nullptr, 0, wt + 2 * 16384, nullptr, hb,
                                     nullptr, 0, (int)Npad, nullptr, nullptr, dinv,
                                     nullptr, nullptr, nullptr);
  agg_kernel<<<aggb, 256, 0, stream>>>(hb, dinv, row_ptr, csr, b3, gb, zout, N);

  // decoder on compact masked rows (d1 gathers z rows via midx; d3 fuses loss)
  mm_kernel<<<mmb, 256, 0, stream>>>(gb, nullptr, 0, wt + 3 * 16384, db1, hb,
                                     nullptr, 1, (int)Npad, midx, mcnt, nullptr,
                                     nullptr, nullptr, nullptr);
  mm_kernel<<<mmb, 256, 0, stream>>>(hb, nullptr, 0, wt + 4 * 16384, db2, gb,
                                     nullptr, 1, (int)Npad, nullptr, mcnt, nullptr,
                                     nullptr, nullptr, nullptr);
  mm_kernel<<<mmb, 256, 0, stream>>>(gb, nullptr, 0, wt + 5 * 16384, db3, nullptr,
                                     nullptr, 0, (int)Npad, nullptr, mcnt, nullptr,
                                     x, midx, accum);

  finalize_kernel<<<1, 1, 0, stream>>>(accum, mcnt, (float*)d_out);
}

// Round 12
// 554.962 us; speedup vs baseline: 1.0960x; 1.0406x over previous
//
#include <hip/hip_runtime.h>
#include <hip/hip_bf16.h>
#include <math.h>

// GraphMAE: 3x GCNConv(relu) encoder -> 3-layer MLP decoder -> masked MSE.
// bf16 activation storage, f32 compute, MFMA bf16 matmuls.
// Round 12: mm back to BM=64 (128 regressed). mm1 fused into the fillp
// dispatch (independent work, concurrent execution). A-loads hoisted ahead
// of MFMA loop. agg/fill at structural floors (rounds 9-11 evidence).
// Outputs: d_out[0] = loss, d_out[1..N*128] = z (f32).

#define DD 128

typedef unsigned short ushort_t;
typedef unsigned int uint_t;
typedef __attribute__((ext_vector_type(8))) short short8;
typedef __attribute__((ext_vector_type(4))) float f32x4;

__device__ __forceinline__ ushort_t f2bf(float f) {
  union { float f; uint_t u; } v; v.f = f;
  uint_t r = v.u + 0x7fff + ((v.u >> 16) & 1);
  return (ushort_t)(r >> 16);
}
__device__ __forceinline__ float u2f(uint_t u) {
  union { uint_t u; float f; } v; v.u = u;
  return v.f;
}

// ---------------- dtype detection (edge_index: i64 vs i32; mask: i32 vs u8) ---
__global__ void detect_kernel(const void* edge, const void* mask,
                              long long E, int N, int* flags) {
  __shared__ int bad_e, bad_m;
  if (threadIdx.x == 0) { bad_e = 0; bad_m = 0; }
  __syncthreads();
  const long long* e64 = (const long long*)edge;
  long long step = E / 1024; if (step < 1) step = 1;
  for (int i = threadIdx.x; i < 1024; i += blockDim.x) {
    long long idx = (long long)i * step;
    if (idx < E) {
      long long v = e64[idx];
      if (v < 0 || v >= N) atomicAdd(&bad_e, 1);
    }
  }
  const int* m32 = (const int*)mask;
  int nw = N / 4;
  for (int i = threadIdx.x; i < nw; i += blockDim.x) {
    int v = m32[i];
    if (v != 0 && v != 1) atomicAdd(&bad_m, 1);
  }
  __syncthreads();
  if (threadIdx.x == 0) {
    flags[0] = (bad_e == 0) ? 1 : 0;
    flags[1] = (bad_m == 0) ? 1 : 0;
  }
}

__device__ __forceinline__ int load_mask(const void* p, int i, int is32) {
  if (is32) return ((const int*)p)[i];
  return (int)((const unsigned char*)p)[i];
}

// ---------------- edge convert to int32 + degree count (fused) --------------
__global__ void cvt_kernel(const void* edge, long long E, int* s32, int* d32,
                           int* deg, const int* flags) {
  int is64 = flags[0];
  long long i = blockIdx.x * (long long)blockDim.x + threadIdx.x;
  long long stride = (long long)gridDim.x * blockDim.x;
  for (; i < E; i += stride) {
    int s, d;
    if (is64) {
      s = (int)((const long long*)edge)[i];
      d = (int)((const long long*)edge)[E + i];
    } else {
      s = ((const int*)edge)[i];
      d = ((const int*)edge)[E + i];
    }
    s32[i] = s;
    d32[i] = d;
    atomicAdd(&deg[d], 1);
  }
}

__global__ void dinv_kernel(const int* deg, float* dinv, int N, int Npad) {
  int i = blockIdx.x * blockDim.x + threadIdx.x;
  if (i < Npad) dinv[i] = (i < N) ? rsqrtf((float)deg[i] + 1.0f) : 0.f;
}

// ---------------- exclusive scan (3-pass) ----------------
__global__ void scan1_kernel(const int* cnt, int* row_excl, int* blocksums, int N) {
  __shared__ int s[1024];
  int t = threadIdx.x, g = blockIdx.x * 1024 + t;
  int v = (g < N) ? cnt[g] : 0;
  s[t] = v;
  __syncthreads();
  for (int off = 1; off < 1024; off <<= 1) {
    int add = (t >= off) ? s[t - off] : 0;
    __syncthreads();
    s[t] += add;
    __syncthreads();
  }
  if (g < N) row_excl[g] = s[t] - v;
  if (t == 1023) blocksums[blockIdx.x] = s[1023];
}

__global__ void scan2_kernel(int* blocksums, int nb, int* row_ptr, int N) {
  if (threadIdx.x == 0 && blockIdx.x == 0) {
    int run = 0;
    for (int b = 0; b < nb; ++b) { int t = blocksums[b]; blocksums[b] = run; run += t; }
    row_ptr[N] = run;
  }
}

__global__ void scan3_kernel(int* row_ptr, const int* blocksums, int* cursor, int N) {
  int g = blockIdx.x * 1024 + threadIdx.x;
  if (g < N) {
    int v = row_ptr[g] + blocksums[blockIdx.x];
    row_ptr[g] = v;
    cursor[g] = v;
  }
}

// ---------------- CSR fill body (dst-range partitioned, int32 streams) ------
__device__ __forceinline__ void fillp_body(const int* __restrict__ s32,
                                           const int* __restrict__ d32,
                                           long long E, int* cursor, int* csr_src,
                                           int N, int bid, int nb) {
  int part = bid & 7;
  int lo = (int)(((long long)N * part) >> 3);
  int hi = (int)(((long long)N * (part + 1)) >> 3);
  long long i = (long long)(bid >> 3) * 256 + threadIdx.x;
  long long stride = (long long)(nb >> 3) * 256;
  for (; i < E; i += stride) {
    int d = d32[i];
    if (d >= lo && d < hi) {
      int s = s32[i];
      int pos = atomicAdd(&cursor[d], 1);
      csr_src[pos] = s;
    }
  }
}

// ---------------- transpose+cast weights: W[k][n] f32 -> WT[n][k] bf16 ------
struct WPtrs { const float* w[6]; };
__global__ void transw_kernel(WPtrs p, ushort_t* wt) {
  int wi = blockIdx.x;
  const float* W = p.w[wi];
  ushort_t* dst = wt + wi * 16384;
  for (int i = threadIdx.x; i < 16384; i += blockDim.x) {
    int k = i >> 7, n = i & 127;
    dst[n * 128 + k] = f2bf(W[i]);
  }
}

// ---------------- mask compaction (order-free) ----------------
__global__ void compact_kernel(const void* mask, const int* flags, int N,
                               int* cnt, int* midx) {
  int i = blockIdx.x * blockDim.x + threadIdx.x;
  if (i < N && load_mask(mask, i, flags[1])) {
    int p = atomicAdd(cnt, 1);
    midx[p] = i;
  }
}

// ---------------- MFMA matmul body: out[rows][128] = A[rows][128] @ W -------
// BM=64 (4 waves x 16 rows). A bf16 row-major OR f32 (in-register cast; rows
// >= nvalid read zero). WT bf16 [n][k] pre-transposed, LDS-staged w/ XOR
// swizzle. All 4 A k-chunks prefetched before the MFMA loop (ILP).
__device__ __forceinline__ void mm_body(
    const ushort_t* __restrict__ A, const float* __restrict__ Af32,
    int nvalid, const ushort_t* __restrict__ WT,
    const float* __restrict__ bias, ushort_t* __restrict__ outb,
    float* __restrict__ outf, int do_relu, int nrows,
    const int* __restrict__ gidx, const int* __restrict__ gM,
    const float* __restrict__ scale,
    const float* __restrict__ xloss, const int* __restrict__ lidx,
    float* __restrict__ accum, int bid, char* lds) {
  int limit = nrows;
  if (gM) limit = *gM;
  if ((long long)bid * 64 >= limit) return;

  int tid = threadIdx.x;
  for (int cid = tid; cid < 2048; cid += 256) {
    int n = cid >> 4, kc = cid & 15;
    int dst = n * 256 + ((kc * 16) ^ ((n & 7) << 4));
    *(float4*)(lds + dst) = *(const float4*)(WT + n * 128 + kc * 8);
  }
  __syncthreads();

  int w = tid >> 6, l = tid & 63;
  long long R0 = (long long)bid * 64 + w * 16;
  f32x4 acc[8];
#pragma unroll
  for (int c = 0; c < 8; ++c) acc[c] = (f32x4){0.f, 0.f, 0.f, 0.f};

  int r_log = (int)R0 + (l & 15);
  long long r_phys = r_log;
  if (gidx) r_phys = (r_log < limit) ? (long long)gidx[r_log] : 0;

  // prefetch all 4 A k-chunks (independent loads in flight)
  short8 a[4];
  if (Af32) {
    if (r_log < nvalid) {
      const float* ar = Af32 + r_phys * 128 + ((l >> 4) << 3);
      float4 f0[4], f1[4];
#pragma unroll
      for (int ks = 0; ks < 4; ++ks) {
        f0[ks] = *(const float4*)(ar + ks * 32);
        f1[ks] = *(const float4*)(ar + ks * 32 + 4);
      }
#pragma unroll
      for (int ks = 0; ks < 4; ++ks) {
        a[ks][0] = (short)f2bf(f0[ks].x); a[ks][1] = (short)f2bf(f0[ks].y);
        a[ks][2] = (short)f2bf(f0[ks].z); a[ks][3] = (short)f2bf(f0[ks].w);
        a[ks][4] = (short)f2bf(f1[ks].x); a[ks][5] = (short)f2bf(f1[ks].y);
        a[ks][6] = (short)f2bf(f1[ks].z); a[ks][7] = (short)f2bf(f1[ks].w);
      }
    } else {
#pragma unroll
      for (int ks = 0; ks < 4; ++ks)
#pragma unroll
        for (int j = 0; j < 8; ++j) a[ks][j] = 0;
    }
  } else {
    const ushort_t* arow = A + r_phys * 128 + ((l >> 4) << 3);
#pragma unroll
    for (int ks = 0; ks < 4; ++ks)
      a[ks] = *(const short8*)(arow + ks * 32);
  }

#pragma unroll
  for (int ks = 0; ks < 4; ++ks) {
#pragma unroll
    for (int c = 0; c < 8; ++c) {
      int nn = c * 16 + (l & 15);
      int kb = ks * 64 + ((l >> 4) << 4);
      short8 b = *(const short8*)(lds + nn * 256 + (kb ^ ((nn & 7) << 4)));
      acc[c] = __builtin_amdgcn_mfma_f32_16x16x32_bf16(a[ks], b, acc[c], 0, 0, 0);
    }
  }

  int store_limit = gM ? limit : nrows;
  long long gr0 = R0 + ((l >> 4) << 2);
  float sc[4] = {1.f, 1.f, 1.f, 1.f};
  if (scale) {
#pragma unroll
    for (int r = 0; r < 4; ++r)
      sc[r] = (gr0 + r < store_limit) ? scale[gr0 + r] : 0.f;
  }
  float local_sq = 0.f;
#pragma unroll
  for (int c = 0; c < 8; ++c) {
    int col = c * 16 + (l & 15);
    float bia = bias ? bias[col] : 0.f;
#pragma unroll
    for (int r = 0; r < 4; ++r) {
      if (gr0 + r < store_limit) {
        float v = acc[c][r] * sc[r] + bia;
        if (do_relu) v = fmaxf(v, 0.f);
        long long idx = (gr0 + r) * 128 + col;
        if (outb) outb[idx] = f2bf(v);
        if (outf) outf[idx] = v;
        if (xloss) {
          int orow = lidx[gr0 + r];
          float d = v - xloss[(size_t)orow * 128 + col];
          local_sq += d * d;
        }
      }
    }
  }
  if (accum) {
    float s = local_sq;
    for (int off2 = 32; off2; off2 >>= 1) s += __shfl_down(s, off2);
    __syncthreads();
    float* red = (float*)lds;
    if (l == 0) red[w] = s;
    __syncthreads();
    if (tid == 0) atomicAdd(accum, red[0] + red[1] + red[2] + red[3]);
  }
}

__launch_bounds__(256, 4)
__global__ void mm_kernel(const ushort_t* __restrict__ A, const float* __restrict__ Af32,
                          int nvalid, const ushort_t* __restrict__ WT,
                          const float* __restrict__ bias, ushort_t* __restrict__ outb,
                          float* __restrict__ outf, int do_relu, int nrows,
                          const int* __restrict__ gidx, const int* __restrict__ gM,
                          const float* __restrict__ scale,
                          const float* __restrict__ xloss, const int* __restrict__ lidx,
                          float* __restrict__ accum) {
  __shared__ __align__(16) char lds[32768];
  mm_body(A, Af32, nvalid, WT, bias, outb, outf, do_relu, nrows, gidx, gM,
          scale, xloss, lidx, accum, blockIdx.x, lds);
}

// Fused dispatch: blocks < mmb run mm1 (x@W1 -> hb), the rest run CSR fill.
// The two are data-independent; mm's MFMA waves fill fill's latency slots.
__launch_bounds__(256, 4)
__global__ void mmfill_kernel(const float* __restrict__ Af32, int nvalid,
                              const ushort_t* __restrict__ WT,
                              ushort_t* __restrict__ outb, int nrows,
                              const float* __restrict__ scale,
                              const int* __restrict__ s32, const int* __restrict__ d32,
                              long long E, int* cursor, int* csr_src, int N,
                              int mmb, int fillb) {
  __shared__ __align__(16) char lds[32768];
  if ((int)blockIdx.x < mmb) {
    mm_body(nullptr, Af32, nvalid, WT, nullptr, outb, nullptr, 0, nrows,
            nullptr, nullptr, scale, nullptr, nullptr, nullptr, blockIdx.x, lds);
  } else {
    fillp_body(s32, d32, E, cursor, csr_src, N, (int)blockIdx.x - mmb, fillb);
  }
}

// ---------------- GCN aggregation (wave/node; ht rows dinv-premultiplied) ----
// out[v] = relu(dv*(sum_{edges} ht[s] + ht[v]) + b); 8 gathers in flight.
__global__ void agg_kernel(const ushort_t* __restrict__ ht, const float* __restrict__ dinv,
                           const int* __restrict__ rp, const int* __restrict__ csr,
                           const float* __restrict__ bias, ushort_t* __restrict__ outb,
                           float* __restrict__ zout, int N) {
  int v = blockIdx.x * 4 + (threadIdx.x >> 6);
  if (v >= N) return;
  int l = threadIdx.x & 63;
  int off = l * 2;
  int e0 = __builtin_amdgcn_readfirstlane(rp[v]);
  int e1 = __builtin_amdgcn_readfirstlane(rp[v + 1]);

  float ax[8], ay[8];
#pragma unroll
  for (int j = 0; j < 8; ++j) { ax[j] = 0.f; ay[j] = 0.f; }

  int deg = e1 - e0;
  int nfull = deg & ~7;
  int efull = e0 + nfull;
  for (int e = e0; e < efull; e += 8) {
#pragma unroll
    for (int j = 0; j < 8; ++j) {
      int s = __builtin_amdgcn_readfirstlane(csr[e + j]);
      uint_t hv = *(const uint_t*)(ht + (size_t)s * 128 + off);
      ax[j] += u2f(hv << 16);
      ay[j] += u2f(hv & 0xffff0000u);
    }
  }
  if (efull < e1) {
#pragma unroll
    for (int j = 0; j < 8; ++j) {
      int idx = efull + j;
      int cs = __builtin_amdgcn_readfirstlane(csr[idx]);  // csr has +16 slack
      int s = (idx < e1) ? cs : N;                        // row N is all-zero
      uint_t hv = *(const uint_t*)(ht + (size_t)s * 128 + off);
      ax[j] += u2f(hv << 16);
      ay[j] += u2f(hv & 0xffff0000u);
    }
  }

  float dv = dinv[v];
  uint_t sv = *(const uint_t*)(ht + (size_t)v * 128 + off);
  float axs = ((ax[0] + ax[1]) + (ax[2] + ax[3])) + ((ax[4] + ax[5]) + (ax[6] + ax[7]));
  float ays = ((ay[0] + ay[1]) + (ay[2] + ay[3])) + ((ay[4] + ay[5]) + (ay[6] + ay[7]));
  axs += u2f(sv << 16);
  ays += u2f(sv & 0xffff0000u);
  float vx = fmaxf(dv * axs + bias[off], 0.f);
  float vy = fmaxf(dv * ays + bias[off + 1], 0.f);
  uint_t packed = (uint_t)f2bf(vx) | ((uint_t)f2bf(vy) << 16);
  *(uint_t*)(outb + (size_t)v * 128 + off) = packed;
  if (zout) {
    *(float2*)(zout + (size_t)v * 128 + off) = make_float2(vx, vy);
  }
}

__global__ void finalize_kernel(const float* accum, const int* cnt, float* out) {
  float denom = fmaxf((float)*cnt, 1.0f) * 128.0f;
  out[0] = *accum / denom;
}

// ---------------- launch ----------------
extern "C" void kernel_launch(void* const* d_in, const int* in_sizes, int n_in,
                              void* d_out, int out_size, void* d_ws, size_t ws_size,
                              hipStream_t stream) {
  const float* x  = (const float*)d_in[0];
  const void* edge = d_in[1];
  const void* mask = d_in[2];
  const float* W1 = (const float*)d_in[3];
  const float* b1 = (const float*)d_in[4];
  const float* W2 = (const float*)d_in[5];
  const float* b2 = (const float*)d_in[6];
  const float* W3 = (const float*)d_in[7];
  const float* b3 = (const float*)d_in[8];
  const float* D1 = (const float*)d_in[9];
  const float* db1 = (const float*)d_in[10];
  const float* D2 = (const float*)d_in[11];
  const float* db2 = (const float*)d_in[12];
  const float* D3 = (const float*)d_in[13];
  const float* db3 = (const float*)d_in[14];

  int N = in_sizes[0] / DD;
  long long E = in_sizes[1] / 2;
  long long Npad = ((long long)N + 63) & ~63LL;

  char* ws = (char*)d_ws;
  size_t p = 0;
  auto alloc = [&](size_t bytes) {
    size_t o = p;
    p = (p + bytes + 255) & ~(size_t)255;
    return o;
  };
  int* flags   = (int*)(ws + alloc(8));
  float* accum = (float*)(ws + alloc(4));
  int* mcnt    = (int*)(ws + alloc(4));
  int* deg     = (int*)(ws + alloc(sizeof(int) * N));
  float* dinv  = (float*)(ws + alloc(sizeof(float) * Npad));
  int* row_ptr = (int*)(ws + alloc(sizeof(int) * (N + 1)));
  int* cursor  = (int*)(ws + alloc(sizeof(int) * N));
  int* bsums   = (int*)(ws + alloc(sizeof(int) * 1024));
  int* midx    = (int*)(ws + alloc(sizeof(int) * N));
  int* s32     = (int*)(ws + alloc(sizeof(int) * E));
  int* d32     = (int*)(ws + alloc(sizeof(int) * E));
  int* csr     = (int*)(ws + alloc(sizeof(int) * (E + 16)));
  ushort_t* wt = (ushort_t*)(ws + alloc(sizeof(ushort_t) * 6 * 128 * 128));
  ushort_t* hb = (ushort_t*)(ws + alloc(sizeof(ushort_t) * (size_t)Npad * DD));
  ushort_t* gb = (ushort_t*)(ws + alloc(sizeof(ushort_t) * (size_t)Npad * DD));

  hipMemsetAsync(deg, 0, sizeof(int) * N, stream);
  hipMemsetAsync(accum, 0, 4, stream);
  hipMemsetAsync(mcnt, 0, 4, stream);
  // zero pad rows (N..Npad): row N is the agg-tail zero gather target.
  size_t padoff = (size_t)N * DD, padbytes = (size_t)(Npad - N) * DD * sizeof(ushort_t);
  hipMemsetAsync(hb + padoff, 0, padbytes, stream);
  hipMemsetAsync(gb + padoff, 0, padbytes, stream);

  // graph prep
  detect_kernel<<<1, 256, 0, stream>>>(edge, mask, E, N, flags);
  cvt_kernel<<<1024, 256, 0, stream>>>(edge, E, s32, d32, deg, flags);
  dinv_kernel<<<(int)((Npad + 255) / 256), 256, 0, stream>>>(deg, dinv, N, (int)Npad);
  int nb = (N + 1023) / 1024;
  scan1_kernel<<<nb, 1024, 0, stream>>>(deg, row_ptr, bsums, N);
  scan2_kernel<<<1, 1, 0, stream>>>(bsums, nb, row_ptr, N);
  scan3_kernel<<<nb, 1024, 0, stream>>>(row_ptr, bsums, cursor, N);
  compact_kernel<<<(N + 255) / 256, 256, 0, stream>>>(mask, flags, N, mcnt, midx);

  // weight prep (before fused mm1)
  WPtrs wp;
  wp.w[0] = W1; wp.w[1] = W2; wp.w[2] = W3;
  wp.w[3] = D1; wp.w[4] = D2; wp.w[5] = D3;
  transw_kernel<<<6, 256, 0, stream>>>(wp, wt);

  float* zout = (float*)d_out + 1;
  int mmb = (int)(Npad / 64);
  int aggb = (N + 3) / 4;
  int fillb = 4096;

  // fused: mm1 (x@W1 -> hb, dinv-scaled) concurrent with CSR fill
  mmfill_kernel<<<mmb + fillb, 256, 0, stream>>>(x, N, wt + 0 * 16384, hb,
                                                 (int)Npad, dinv, s32, d32, E,
                                                 cursor, csr, N, mmb, fillb);

  // encoder (mm stores ht = dinv * (A@W) in bf16)
  agg_kernel<<<aggb, 256, 0, stream>>>(hb, dinv, row_ptr, csr, b1, gb, nullptr, N);
  mm_kernel<<<mmb, 256, 0, stream>>>(gb, nullptr, 0, wt + 1 * 16384, nullptr, hb,
                                     nullptr, 0, (int)Npad, nullptr, nullptr, dinv,
                                     nullptr, nullptr, nullptr);
  agg_kernel<<<aggb, 256, 0, stream>>>(hb, dinv, row_ptr, csr, b2, gb, nullptr, N);
  mm_kernel<<<mmb, 256, 0, stream>>>(gb, nullptr, 0, wt + 2 * 16384, nullptr, hb,
                                     nullptr, 0, (int)Npad, nullptr, nullptr, dinv,
                                     nullptr, nullptr, nullptr);
  agg_kernel<<<aggb, 256, 0, stream>>>(hb, dinv, row_ptr, csr, b3, gb, zout, N);

  // decoder on compact masked rows (d1 gathers z rows via midx; d3 fuses loss)
  mm_kernel<<<mmb, 256, 0, stream>>>(gb, nullptr, 0, wt + 3 * 16384, db1, hb,
                                     nullptr, 1, (int)Npad, midx, mcnt, nullptr,
                                     nullptr, nullptr, nullptr);
  mm_kernel<<<mmb, 256, 0, stream>>>(hb, nullptr, 0, wt + 4 * 16384, db2, gb,
                                     nullptr, 1, (int)Npad, nullptr, mcnt, nullptr,
                                     nullptr, nullptr, nullptr);
  mm_kernel<<<mmb, 256, 0, stream>>>(gb, nullptr, 0, wt + 5 * 16384, db3, nullptr,
                                     nullptr, 0, (int)Npad, nullptr, mcnt, nullptr,
                                     x, midx, accum);

  finalize_kernel<<<1, 1, 0, stream>>>(accum, mcnt, (float*)d_out);
}

// Round 13
// 544.992 us; speedup vs baseline: 1.1160x; 1.0183x over previous
//
#include <hip/hip_runtime.h>
#include <hip/hip_bf16.h>
#include <math.h>

// GraphMAE: 3x GCNConv(relu) encoder -> 3-layer MLP decoder -> masked MSE.
// bf16 activation storage, f32 compute, MFMA bf16 matmuls.
// Round 13: mm epilogue rebuilt - accumulator transposed through LDS (row
// stride 272B) so each thread issues 4x16B coalesced stores instead of 32x2B
// scattered ushort stores. mm1 stays fused with CSR fill (round 12 win).
// Outputs: d_out[0] = loss, d_out[1..N*128] = z (f32).

#define DD 128

typedef unsigned short ushort_t;
typedef unsigned int uint_t;
typedef __attribute__((ext_vector_type(8))) short short8;
typedef __attribute__((ext_vector_type(4))) float f32x4;

__device__ __forceinline__ ushort_t f2bf(float f) {
  union { float f; uint_t u; } v; v.f = f;
  uint_t r = v.u + 0x7fff + ((v.u >> 16) & 1);
  return (ushort_t)(r >> 16);
}
__device__ __forceinline__ float u2f(uint_t u) {
  union { uint_t u; float f; } v; v.u = u;
  return v.f;
}

// ---------------- dtype detection (edge_index: i64 vs i32; mask: i32 vs u8) ---
__global__ void detect_kernel(const void* edge, const void* mask,
                              long long E, int N, int* flags) {
  __shared__ int bad_e, bad_m;
  if (threadIdx.x == 0) { bad_e = 0; bad_m = 0; }
  __syncthreads();
  const long long* e64 = (const long long*)edge;
  long long step = E / 1024; if (step < 1) step = 1;
  for (int i = threadIdx.x; i < 1024; i += blockDim.x) {
    long long idx = (long long)i * step;
    if (idx < E) {
      long long v = e64[idx];
      if (v < 0 || v >= N) atomicAdd(&bad_e, 1);
    }
  }
  const int* m32 = (const int*)mask;
  int nw = N / 4;
  for (int i = threadIdx.x; i < nw; i += blockDim.x) {
    int v = m32[i];
    if (v != 0 && v != 1) atomicAdd(&bad_m, 1);
  }
  __syncthreads();
  if (threadIdx.x == 0) {
    flags[0] = (bad_e == 0) ? 1 : 0;
    flags[1] = (bad_m == 0) ? 1 : 0;
  }
}

__device__ __forceinline__ int load_mask(const void* p, int i, int is32) {
  if (is32) return ((const int*)p)[i];
  return (int)((const unsigned char*)p)[i];
}

// ---------------- edge convert to int32 + degree count (fused) --------------
__global__ void cvt_kernel(const void* edge, long long E, int* s32, int* d32,
                           int* deg, const int* flags) {
  int is64 = flags[0];
  long long i = blockIdx.x * (long long)blockDim.x + threadIdx.x;
  long long stride = (long long)gridDim.x * blockDim.x;
  for (; i < E; i += stride) {
    int s, d;
    if (is64) {
      s = (int)((const long long*)edge)[i];
      d = (int)((const long long*)edge)[E + i];
    } else {
      s = ((const int*)edge)[i];
      d = ((const int*)edge)[E + i];
    }
    s32[i] = s;
    d32[i] = d;
    atomicAdd(&deg[d], 1);
  }
}

__global__ void dinv_kernel(const int* deg, float* dinv, int N, int Npad) {
  int i = blockIdx.x * blockDim.x + threadIdx.x;
  if (i < Npad) dinv[i] = (i < N) ? rsqrtf((float)deg[i] + 1.0f) : 0.f;
}

// ---------------- exclusive scan (3-pass) ----------------
__global__ void scan1_kernel(const int* cnt, int* row_excl, int* blocksums, int N) {
  __shared__ int s[1024];
  int t = threadIdx.x, g = blockIdx.x * 1024 + t;
  int v = (g < N) ? cnt[g] : 0;
  s[t] = v;
  __syncthreads();
  for (int off = 1; off < 1024; off <<= 1) {
    int add = (t >= off) ? s[t - off] : 0;
    __syncthreads();
    s[t] += add;
    __syncthreads();
  }
  if (g < N) row_excl[g] = s[t] - v;
  if (t == 1023) blocksums[blockIdx.x] = s[1023];
}

__global__ void scan2_kernel(int* blocksums, int nb, int* row_ptr, int N) {
  if (threadIdx.x == 0 && blockIdx.x == 0) {
    int run = 0;
    for (int b = 0; b < nb; ++b) { int t = blocksums[b]; blocksums[b] = run; run += t; }
    row_ptr[N] = run;
  }
}

__global__ void scan3_kernel(int* row_ptr, const int* blocksums, int* cursor, int N) {
  int g = blockIdx.x * 1024 + threadIdx.x;
  if (g < N) {
    int v = row_ptr[g] + blocksums[blockIdx.x];
    row_ptr[g] = v;
    cursor[g] = v;
  }
}

// ---------------- CSR fill body (dst-range partitioned, int32 streams) ------
__device__ __forceinline__ void fillp_body(const int* __restrict__ s32,
                                           const int* __restrict__ d32,
                                           long long E, int* cursor, int* csr_src,
                                           int N, int bid, int nb) {
  int part = bid & 7;
  int lo = (int)(((long long)N * part) >> 3);
  int hi = (int)(((long long)N * (part + 1)) >> 3);
  long long i = (long long)(bid >> 3) * 256 + threadIdx.x;
  long long stride = (long long)(nb >> 3) * 256;
  for (; i < E; i += stride) {
    int d = d32[i];
    if (d >= lo && d < hi) {
      int s = s32[i];
      int pos = atomicAdd(&cursor[d], 1);
      csr_src[pos] = s;
    }
  }
}

// ---------------- transpose+cast weights: W[k][n] f32 -> WT[n][k] bf16 ------
struct WPtrs { const float* w[6]; };
__global__ void transw_kernel(WPtrs p, ushort_t* wt) {
  int wi = blockIdx.x;
  const float* W = p.w[wi];
  ushort_t* dst = wt + wi * 16384;
  for (int i = threadIdx.x; i < 16384; i += blockDim.x) {
    int k = i >> 7, n = i & 127;
    dst[n * 128 + k] = f2bf(W[i]);
  }
}

// ---------------- mask compaction (order-free) ----------------
__global__ void compact_kernel(const void* mask, const int* flags, int N,
                               int* cnt, int* midx) {
  int i = blockIdx.x * blockDim.x + threadIdx.x;
  if (i < N && load_mask(mask, i, flags[1])) {
    int p = atomicAdd(cnt, 1);
    midx[p] = i;
  }
}

// ---------------- MFMA matmul body: out[rows][128] = A[rows][128] @ W -------
// BM=64 (4 waves x 16 rows). A bf16 row-major OR f32 (in-register cast; rows
// >= nvalid read zero). WT bf16 [n][k] pre-transposed, LDS-staged w/ XOR
// swizzle. Output transposed through LDS (stride 272B) -> 4x16B coalesced
// stores per thread. Loss path (accum) skips stores entirely.
__device__ __forceinline__ void mm_body(
    const ushort_t* __restrict__ A, const float* __restrict__ Af32,
    int nvalid, const ushort_t* __restrict__ WT,
    const float* __restrict__ bias, ushort_t* __restrict__ outb,
    int do_relu, int nrows,
    const int* __restrict__ gidx, const int* __restrict__ gM,
    const float* __restrict__ scale,
    const float* __restrict__ xloss, const int* __restrict__ lidx,
    float* __restrict__ accum, int bid, char* lds) {
  int limit = nrows;
  if (gM) limit = *gM;
  if ((long long)bid * 64 >= limit) return;

  int tid = threadIdx.x;
  for (int cid = tid; cid < 2048; cid += 256) {
    int n = cid >> 4, kc = cid & 15;
    int dst = n * 256 + ((kc * 16) ^ ((n & 7) << 4));
    *(float4*)(lds + dst) = *(const float4*)(WT + n * 128 + kc * 8);
  }
  __syncthreads();

  int w = tid >> 6, l = tid & 63;
  long long R0 = (long long)bid * 64 + w * 16;
  f32x4 acc[8];
#pragma unroll
  for (int c = 0; c < 8; ++c) acc[c] = (f32x4){0.f, 0.f, 0.f, 0.f};

  int r_log = (int)R0 + (l & 15);
  long long r_phys = r_log;
  if (gidx) r_phys = (r_log < limit) ? (long long)gidx[r_log] : 0;

  // prefetch all 4 A k-chunks (independent loads in flight)
  short8 a[4];
  if (Af32) {
    if (r_log < nvalid) {
      const float* ar = Af32 + r_phys * 128 + ((l >> 4) << 3);
      float4 f0[4], f1[4];
#pragma unroll
      for (int ks = 0; ks < 4; ++ks) {
        f0[ks] = *(const float4*)(ar + ks * 32);
        f1[ks] = *(const float4*)(ar + ks * 32 + 4);
      }
#pragma unroll
      for (int ks = 0; ks < 4; ++ks) {
        a[ks][0] = (short)f2bf(f0[ks].x); a[ks][1] = (short)f2bf(f0[ks].y);
        a[ks][2] = (short)f2bf(f0[ks].z); a[ks][3] = (short)f2bf(f0[ks].w);
        a[ks][4] = (short)f2bf(f1[ks].x); a[ks][5] = (short)f2bf(f1[ks].y);
        a[ks][6] = (short)f2bf(f1[ks].z); a[ks][7] = (short)f2bf(f1[ks].w);
      }
    } else {
#pragma unroll
      for (int ks = 0; ks < 4; ++ks)
#pragma unroll
        for (int j = 0; j < 8; ++j) a[ks][j] = 0;
    }
  } else {
    const ushort_t* arow = A + r_phys * 128 + ((l >> 4) << 3);
#pragma unroll
    for (int ks = 0; ks < 4; ++ks)
      a[ks] = *(const short8*)(arow + ks * 32);
  }

#pragma unroll
  for (int ks = 0; ks < 4; ++ks) {
#pragma unroll
    for (int c = 0; c < 8; ++c) {
      int nn = c * 16 + (l & 15);
      int kb = ks * 64 + ((l >> 4) << 4);
      short8 b = *(const short8*)(lds + nn * 256 + (kb ^ ((nn & 7) << 4)));
      acc[c] = __builtin_amdgcn_mfma_f32_16x16x32_bf16(a[ks], b, acc[c], 0, 0, 0);
    }
  }

  int store_limit = gM ? limit : nrows;
  long long gr0 = R0 + ((l >> 4) << 2);
  float sc[4] = {1.f, 1.f, 1.f, 1.f};
  if (scale) {
#pragma unroll
    for (int r = 0; r < 4; ++r)
      sc[r] = (gr0 + r < store_limit) ? scale[gr0 + r] : 0.f;
  }

  if (accum) {  // fused masked-MSE epilogue (no stores)
    float local_sq = 0.f;
#pragma unroll
    for (int c = 0; c < 8; ++c) {
      int col = c * 16 + (l & 15);
      float bia = bias ? bias[col] : 0.f;
#pragma unroll
      for (int r = 0; r < 4; ++r) {
        if (gr0 + r < store_limit) {
          float v = acc[c][r] * sc[r] + bia;
          if (do_relu) v = fmaxf(v, 0.f);
          int orow = lidx[gr0 + r];
          float d = v - xloss[(size_t)orow * 128 + col];
          local_sq += d * d;
        }
      }
    }
    float s = local_sq;
    for (int off2 = 32; off2; off2 >>= 1) s += __shfl_down(s, off2);
    __syncthreads();
    float* red = (float*)lds;
    if (l == 0) red[w] = s;
    __syncthreads();
    if (tid == 0) atomicAdd(accum, red[0] + red[1] + red[2] + red[3]);
    return;
  }

  // store path: transpose through LDS (stride 272B), then 4x16B per thread
  __syncthreads();  // all waves done reading W from LDS
  int rbase = w * 16 + ((l >> 4) << 2);
#pragma unroll
  for (int c = 0; c < 8; ++c) {
    int col = c * 16 + (l & 15);
    float bia = bias ? bias[col] : 0.f;
#pragma unroll
    for (int r = 0; r < 4; ++r) {
      float v = acc[c][r] * sc[r] + bia;
      if (do_relu) v = fmaxf(v, 0.f);
      *(ushort_t*)(lds + (rbase + r) * 272 + col * 2) = f2bf(v);
    }
  }
  __syncthreads();
  int row = tid >> 2, ck = tid & 3;
  long long grow = (long long)bid * 64 + row;
  if (grow < store_limit) {
    const char* src = lds + row * 272 + ck * 64;
    ushort_t* dstp = outb + grow * 128 + ck * 32;
    *(short8*)(dstp)      = *(const short8*)(src);
    *(short8*)(dstp + 8)  = *(const short8*)(src + 16);
    *(short8*)(dstp + 16) = *(const short8*)(src + 32);
    *(short8*)(dstp + 24) = *(const short8*)(src + 48);
  }
}

__launch_bounds__(256, 4)
__global__ void mm_kernel(const ushort_t* __restrict__ A, const float* __restrict__ Af32,
                          int nvalid, const ushort_t* __restrict__ WT,
                          const float* __restrict__ bias, ushort_t* __restrict__ outb,
                          int do_relu, int nrows,
                          const int* __restrict__ gidx, const int* __restrict__ gM,
                          const float* __restrict__ scale,
                          const float* __restrict__ xloss, const int* __restrict__ lidx,
                          float* __restrict__ accum) {
  __shared__ __align__(16) char lds[32768];
  mm_body(A, Af32, nvalid, WT, bias, outb, do_relu, nrows, gidx, gM,
          scale, xloss, lidx, accum, blockIdx.x, lds);
}

// Fused dispatch: blocks < mmb run mm1 (x@W1 -> hb), the rest run CSR fill.
__launch_bounds__(256, 4)
__global__ void mmfill_kernel(const float* __restrict__ Af32, int nvalid,
                              const ushort_t* __restrict__ WT,
                              ushort_t* __restrict__ outb, int nrows,
                              const float* __restrict__ scale,
                              const int* __restrict__ s32, const int* __restrict__ d32,
                              long long E, int* cursor, int* csr_src, int N,
                              int mmb, int fillb) {
  __shared__ __align__(16) char lds[32768];
  if ((int)blockIdx.x < mmb) {
    mm_body(nullptr, Af32, nvalid, WT, nullptr, outb, 0, nrows,
            nullptr, nullptr, scale, nullptr, nullptr, nullptr, blockIdx.x, lds);
  } else {
    fillp_body(s32, d32, E, cursor, csr_src, N, (int)blockIdx.x - mmb, fillb);
  }
}

// ---------------- GCN aggregation (wave/node; ht rows dinv-premultiplied) ----
// out[v] = relu(dv*(sum_{edges} ht[s] + ht[v]) + b); 8 gathers in flight.
__global__ void agg_kernel(const ushort_t* __restrict__ ht, const float* __restrict__ dinv,
                           const int* __restrict__ rp, const int* __restrict__ csr,
                           const float* __restrict__ bias, ushort_t* __restrict__ outb,
                           float* __restrict__ zout, int N) {
  int v = blockIdx.x * 4 + (threadIdx.x >> 6);
  if (v >= N) return;
  int l = threadIdx.x & 63;
  int off = l * 2;
  int e0 = __builtin_amdgcn_readfirstlane(rp[v]);
  int e1 = __builtin_amdgcn_readfirstlane(rp[v + 1]);

  float ax[8], ay[8];
#pragma unroll
  for (int j = 0; j < 8; ++j) { ax[j] = 0.f; ay[j] = 0.f; }

  int deg = e1 - e0;
  int nfull = deg & ~7;
  int efull = e0 + nfull;
  for (int e = e0; e < efull; e += 8) {
#pragma unroll
    for (int j = 0; j < 8; ++j) {
      int s = __builtin_amdgcn_readfirstlane(csr[e + j]);
      uint_t hv = *(const uint_t*)(ht + (size_t)s * 128 + off);
      ax[j] += u2f(hv << 16);
      ay[j] += u2f(hv & 0xffff0000u);
    }
  }
  if (efull < e1) {
#pragma unroll
    for (int j = 0; j < 8; ++j) {
      int idx = efull + j;
      int cs = __builtin_amdgcn_readfirstlane(csr[idx]);  // csr has +16 slack
      int s = (idx < e1) ? cs : N;                        // row N is all-zero
      uint_t hv = *(const uint_t*)(ht + (size_t)s * 128 + off);
      ax[j] += u2f(hv << 16);
      ay[j] += u2f(hv & 0xffff0000u);
    }
  }

  float dv = dinv[v];
  uint_t sv = *(const uint_t*)(ht + (size_t)v * 128 + off);
  float axs = ((ax[0] + ax[1]) + (ax[2] + ax[3])) + ((ax[4] + ax[5]) + (ax[6] + ax[7]));
  float ays = ((ay[0] + ay[1]) + (ay[2] + ay[3])) + ((ay[4] + ay[5]) + (ay[6] + ay[7]));
  axs += u2f(sv << 16);
  ays += u2f(sv & 0xffff0000u);
  float vx = fmaxf(dv * axs + bias[off], 0.f);
  float vy = fmaxf(dv * ays + bias[off + 1], 0.f);
  uint_t packed = (uint_t)f2bf(vx) | ((uint_t)f2bf(vy) << 16);
  *(uint_t*)(outb + (size_t)v * 128 + off) = packed;
  if (zout) {
    *(float2*)(zout + (size_t)v * 128 + off) = make_float2(vx, vy);
  }
}

__global__ void finalize_kernel(const float* accum, const int* cnt, float* out) {
  float denom = fmaxf((float)*cnt, 1.0f) * 128.0f;
  out[0] = *accum / denom;
}

// ---------------- launch ----------------
extern "C" void kernel_launch(void* const* d_in, const int* in_sizes, int n_in,
                              void* d_out, int out_size, void* d_ws, size_t ws_size,
                              hipStream_t stream) {
  const float* x  = (const float*)d_in[0];
  const void* edge = d_in[1];
  const void* mask = d_in[2];
  const float* W1 = (const float*)d_in[3];
  const float* b1 = (const float*)d_in[4];
  const float* W2 = (const float*)d_in[5];
  const float* b2 = (const float*)d_in[6];
  const float* W3 = (const float*)d_in[7];
  const float* b3 = (const float*)d_in[8];
  const float* D1 = (const float*)d_in[9];
  const float* db1 = (const float*)d_in[10];
  const float* D2 = (const float*)d_in[11];
  const float* db2 = (const float*)d_in[12];
  const float* D3 = (const float*)d_in[13];
  const float* db3 = (const float*)d_in[14];

  int N = in_sizes[0] / DD;
  long long E = in_sizes[1] / 2;
  long long Npad = ((long long)N + 63) & ~63LL;

  char* ws = (char*)d_ws;
  size_t p = 0;
  auto alloc = [&](size_t bytes) {
    size_t o = p;
    p = (p + bytes + 255) & ~(size_t)255;
    return o;
  };
  int* flags   = (int*)(ws + alloc(8));
  float* accum = (float*)(ws + alloc(4));
  int* mcnt    = (int*)(ws + alloc(4));
  int* deg     = (int*)(ws + alloc(sizeof(int) * N));
  float* dinv  = (float*)(ws + alloc(sizeof(float) * Npad));
  int* row_ptr = (int*)(ws + alloc(sizeof(int) * (N + 1)));
  int* cursor  = (int*)(ws + alloc(sizeof(int) * N));
  int* bsums   = (int*)(ws + alloc(sizeof(int) * 1024));
  int* midx    = (int*)(ws + alloc(sizeof(int) * N));
  int* s32     = (int*)(ws + alloc(sizeof(int) * E));
  int* d32     = (int*)(ws + alloc(sizeof(int) * E));
  int* csr     = (int*)(ws + alloc(sizeof(int) * (E + 16)));
  ushort_t* wt = (ushort_t*)(ws + alloc(sizeof(ushort_t) * 6 * 128 * 128));
  ushort_t* hb = (ushort_t*)(ws + alloc(sizeof(ushort_t) * (size_t)Npad * DD));
  ushort_t* gb = (ushort_t*)(ws + alloc(sizeof(ushort_t) * (size_t)Npad * DD));

  hipMemsetAsync(deg, 0, sizeof(int) * N, stream);
  hipMemsetAsync(accum, 0, 4, stream);
  hipMemsetAsync(mcnt, 0, 4, stream);
  // zero pad rows (N..Npad): row N is the agg-tail zero gather target.
  size_t padoff = (size_t)N * DD, padbytes = (size_t)(Npad - N) * DD * sizeof(ushort_t);
  hipMemsetAsync(hb + padoff, 0, padbytes, stream);
  hipMemsetAsync(gb + padoff, 0, padbytes, stream);

  // graph prep
  detect_kernel<<<1, 256, 0, stream>>>(edge, mask, E, N, flags);
  cvt_kernel<<<1024, 256, 0, stream>>>(edge, E, s32, d32, deg, flags);
  dinv_kernel<<<(int)((Npad + 255) / 256), 256, 0, stream>>>(deg, dinv, N, (int)Npad);
  int nb = (N + 1023) / 1024;
  scan1_kernel<<<nb, 1024, 0, stream>>>(deg, row_ptr, bsums, N);
  scan2_kernel<<<1, 1, 0, stream>>>(bsums, nb, row_ptr, N);
  scan3_kernel<<<nb, 1024, 0, stream>>>(row_ptr, bsums, cursor, N);
  compact_kernel<<<(N + 255) / 256, 256, 0, stream>>>(mask, flags, N, mcnt, midx);

  // weight prep (before fused mm1)
  WPtrs wp;
  wp.w[0] = W1; wp.w[1] = W2; wp.w[2] = W3;
  wp.w[3] = D1; wp.w[4] = D2; wp.w[5] = D3;
  transw_kernel<<<6, 256, 0, stream>>>(wp, wt);

  float* zout = (float*)d_out + 1;
  int mmb = (int)(Npad / 64);
  int aggb = (N + 3) / 4;
  int fillb = 4096;

  // fused: mm1 (x@W1 -> hb, dinv-scaled) concurrent with CSR fill
  mmfill_kernel<<<mmb + fillb, 256, 0, stream>>>(x, N, wt + 0 * 16384, hb,
                                                 (int)Npad, dinv, s32, d32, E,
                                                 cursor, csr, N, mmb, fillb);

  // encoder (mm stores ht = dinv * (A@W) in bf16)
  agg_kernel<<<aggb, 256, 0, stream>>>(hb, dinv, row_ptr, csr, b1, gb, nullptr, N);
  mm_kernel<<<mmb, 256, 0, stream>>>(gb, nullptr, 0, wt + 1 * 16384, nullptr, hb,
                                     0, (int)Npad, nullptr, nullptr, dinv,
                                     nullptr, nullptr, nullptr);
  agg_kernel<<<aggb, 256, 0, stream>>>(hb, dinv, row_ptr, csr, b2, gb, nullptr, N);
  mm_kernel<<<mmb, 256, 0, stream>>>(gb, nullptr, 0, wt + 2 * 16384, nullptr, hb,
                                     0, (int)Npad, nullptr, nullptr, dinv,
                                     nullptr, nullptr, nullptr);
  agg_kernel<<<aggb, 256, 0, stream>>>(hb, dinv, row_ptr, csr, b3, gb, zout, N);

  // decoder on compact masked rows (d1 gathers z rows via midx; d3 fuses loss)
  mm_kernel<<<mmb, 256, 0, stream>>>(gb, nullptr, 0, wt + 3 * 16384, db1, hb,
                                     1, (int)Npad, midx, mcnt, nullptr,
                                     nullptr, nullptr, nullptr);
  mm_kernel<<<mmb, 256, 0, stream>>>(hb, nullptr, 0, wt + 4 * 16384, db2, gb,
                                     1, (int)Npad, nullptr, mcnt, nullptr,
                                     nullptr, nullptr, nullptr);
  mm_kernel<<<mmb, 256, 0, stream>>>(gb, nullptr, 0, wt + 5 * 16384, db3, nullptr,
                                     0, (int)Npad, nullptr, mcnt, nullptr,
                                     x, midx, accum);

  finalize_kernel<<<1, 1, 0, stream>>>(accum, mcnt, (float*)d_out);
}

// Round 14
// 536.566 us; speedup vs baseline: 1.1336x; 1.0157x over previous
//
#include <hip/hip_runtime.h>
#include <hip/hip_bf16.h>
#include <math.h>

// GraphMAE: 3x GCNConv(relu) encoder -> 3-layer MLP decoder -> masked MSE.
// bf16 activation storage, f32 compute, MFMA bf16 matmuls.
// Round 14: full decoder fused into ONE kernel (dec_kernel): d1 -> LDS tile
// -> d2 -> LDS tile -> d3 -> fused masked-MSE. No decoder global stores.
// Encoder unchanged (mm1 fused with CSR fill; LDS-transposed mm stores).
// Outputs: d_out[0] = loss, d_out[1..N*128] = z (f32).

#define DD 128

typedef unsigned short ushort_t;
typedef unsigned int uint_t;
typedef __attribute__((ext_vector_type(8))) short short8;
typedef __attribute__((ext_vector_type(4))) float f32x4;

__device__ __forceinline__ ushort_t f2bf(float f) {
  union { float f; uint_t u; } v; v.f = f;
  uint_t r = v.u + 0x7fff + ((v.u >> 16) & 1);
  return (ushort_t)(r >> 16);
}
__device__ __forceinline__ float u2f(uint_t u) {
  union { uint_t u; float f; } v; v.u = u;
  return v.f;
}

// ---------------- dtype detection (edge_index: i64 vs i32; mask: i32 vs u8) ---
__global__ void detect_kernel(const void* edge, const void* mask,
                              long long E, int N, int* flags) {
  __shared__ int bad_e, bad_m;
  if (threadIdx.x == 0) { bad_e = 0; bad_m = 0; }
  __syncthreads();
  const long long* e64 = (const long long*)edge;
  long long step = E / 1024; if (step < 1) step = 1;
  for (int i = threadIdx.x; i < 1024; i += blockDim.x) {
    long long idx = (long long)i * step;
    if (idx < E) {
      long long v = e64[idx];
      if (v < 0 || v >= N) atomicAdd(&bad_e, 1);
    }
  }
  const int* m32 = (const int*)mask;
  int nw = N / 4;
  for (int i = threadIdx.x; i < nw; i += blockDim.x) {
    int v = m32[i];
    if (v != 0 && v != 1) atomicAdd(&bad_m, 1);
  }
  __syncthreads();
  if (threadIdx.x == 0) {
    flags[0] = (bad_e == 0) ? 1 : 0;
    flags[1] = (bad_m == 0) ? 1 : 0;
  }
}

__device__ __forceinline__ int load_mask(const void* p, int i, int is32) {
  if (is32) return ((const int*)p)[i];
  return (int)((const unsigned char*)p)[i];
}

// ---------------- edge convert to int32 + degree count (fused) --------------
__global__ void cvt_kernel(const void* edge, long long E, int* s32, int* d32,
                           int* deg, const int* flags) {
  int is64 = flags[0];
  long long i = blockIdx.x * (long long)blockDim.x + threadIdx.x;
  long long stride = (long long)gridDim.x * blockDim.x;
  for (; i < E; i += stride) {
    int s, d;
    if (is64) {
      s = (int)((const long long*)edge)[i];
      d = (int)((const long long*)edge)[E + i];
    } else {
      s = ((const int*)edge)[i];
      d = ((const int*)edge)[E + i];
    }
    s32[i] = s;
    d32[i] = d;
    atomicAdd(&deg[d], 1);
  }
}

__global__ void dinv_kernel(const int* deg, float* dinv, int N, int Npad) {
  int i = blockIdx.x * blockDim.x + threadIdx.x;
  if (i < Npad) dinv[i] = (i < N) ? rsqrtf((float)deg[i] + 1.0f) : 0.f;
}

// ---------------- exclusive scan (3-pass) ----------------
__global__ void scan1_kernel(const int* cnt, int* row_excl, int* blocksums, int N) {
  __shared__ int s[1024];
  int t = threadIdx.x, g = blockIdx.x * 1024 + t;
  int v = (g < N) ? cnt[g] : 0;
  s[t] = v;
  __syncthreads();
  for (int off = 1; off < 1024; off <<= 1) {
    int add = (t >= off) ? s[t - off] : 0;
    __syncthreads();
    s[t] += add;
    __syncthreads();
  }
  if (g < N) row_excl[g] = s[t] - v;
  if (t == 1023) blocksums[blockIdx.x] = s[1023];
}

__global__ void scan2_kernel(int* blocksums, int nb, int* row_ptr, int N) {
  if (threadIdx.x == 0 && blockIdx.x == 0) {
    int run = 0;
    for (int b = 0; b < nb; ++b) { int t = blocksums[b]; blocksums[b] = run; run += t; }
    row_ptr[N] = run;
  }
}

__global__ void scan3_kernel(int* row_ptr, const int* blocksums, int* cursor, int N) {
  int g = blockIdx.x * 1024 + threadIdx.x;
  if (g < N) {
    int v = row_ptr[g] + blocksums[blockIdx.x];
    row_ptr[g] = v;
    cursor[g] = v;
  }
}

// ---------------- CSR fill body (dst-range partitioned, int32 streams) ------
__device__ __forceinline__ void fillp_body(const int* __restrict__ s32,
                                           const int* __restrict__ d32,
                                           long long E, int* cursor, int* csr_src,
                                           int N, int bid, int nb) {
  int part = bid & 7;
  int lo = (int)(((long long)N * part) >> 3);
  int hi = (int)(((long long)N * (part + 1)) >> 3);
  long long i = (long long)(bid >> 3) * 256 + threadIdx.x;
  long long stride = (long long)(nb >> 3) * 256;
  for (; i < E; i += stride) {
    int d = d32[i];
    if (d >= lo && d < hi) {
      int s = s32[i];
      int pos = atomicAdd(&cursor[d], 1);
      csr_src[pos] = s;
    }
  }
}

// ---------------- transpose+cast weights: W[k][n] f32 -> WT[n][k] bf16 ------
struct WPtrs { const float* w[6]; };
__global__ void transw_kernel(WPtrs p, ushort_t* wt) {
  int wi = blockIdx.x;
  const float* W = p.w[wi];
  ushort_t* dst = wt + wi * 16384;
  for (int i = threadIdx.x; i < 16384; i += blockDim.x) {
    int k = i >> 7, n = i & 127;
    dst[n * 128 + k] = f2bf(W[i]);
  }
}

// ---------------- mask compaction (order-free) ----------------
__global__ void compact_kernel(const void* mask, const int* flags, int N,
                               int* cnt, int* midx) {
  int i = blockIdx.x * blockDim.x + threadIdx.x;
  if (i < N && load_mask(mask, i, flags[1])) {
    int p = atomicAdd(cnt, 1);
    midx[p] = i;
  }
}

// ---------------- shared helpers for MFMA layers ----------------
__device__ __forceinline__ void stage_w(const ushort_t* __restrict__ WT, char* ldsW) {
  int tid = threadIdx.x;
  for (int cid = tid; cid < 2048; cid += 256) {
    int n = cid >> 4, kc = cid & 15;
    int dst = n * 256 + ((kc * 16) ^ ((n & 7) << 4));
    *(float4*)(ldsW + dst) = *(const float4*)(WT + n * 128 + kc * 8);
  }
}

__device__ __forceinline__ void mfma_128(const short8 a[4], f32x4 acc[8],
                                         const char* ldsW, int l) {
#pragma unroll
  for (int ks = 0; ks < 4; ++ks) {
#pragma unroll
    for (int c = 0; c < 8; ++c) {
      int nn = c * 16 + (l & 15);
      int kb = ks * 64 + ((l >> 4) << 4);
      short8 b = *(const short8*)(ldsW + nn * 256 + (kb ^ ((nn & 7) << 4)));
      acc[c] = __builtin_amdgcn_mfma_f32_16x16x32_bf16(a[ks], b, acc[c], 0, 0, 0);
    }
  }
}

// ---------------- MFMA matmul body (encoder): out = A@W, LDS-transposed store
__device__ __forceinline__ void mm_body(
    const ushort_t* __restrict__ A, const float* __restrict__ Af32,
    int nvalid, const ushort_t* __restrict__ WT,
    ushort_t* __restrict__ outb, int nrows,
    const float* __restrict__ scale, int bid, char* lds) {
  if ((long long)bid * 64 >= nrows) return;

  stage_w(WT, lds);
  __syncthreads();

  int tid = threadIdx.x, w = tid >> 6, l = tid & 63;
  long long R0 = (long long)bid * 64 + w * 16;
  f32x4 acc[8];
#pragma unroll
  for (int c = 0; c < 8; ++c) acc[c] = (f32x4){0.f, 0.f, 0.f, 0.f};

  int r_log = (int)R0 + (l & 15);
  short8 a[4];
  if (Af32) {
    if (r_log < nvalid) {
      const float* ar = Af32 + (long long)r_log * 128 + ((l >> 4) << 3);
      float4 f0[4], f1[4];
#pragma unroll
      for (int ks = 0; ks < 4; ++ks) {
        f0[ks] = *(const float4*)(ar + ks * 32);
        f1[ks] = *(const float4*)(ar + ks * 32 + 4);
      }
#pragma unroll
      for (int ks = 0; ks < 4; ++ks) {
        a[ks][0] = (short)f2bf(f0[ks].x); a[ks][1] = (short)f2bf(f0[ks].y);
        a[ks][2] = (short)f2bf(f0[ks].z); a[ks][3] = (short)f2bf(f0[ks].w);
        a[ks][4] = (short)f2bf(f1[ks].x); a[ks][5] = (short)f2bf(f1[ks].y);
        a[ks][6] = (short)f2bf(f1[ks].z); a[ks][7] = (short)f2bf(f1[ks].w);
      }
    } else {
#pragma unroll
      for (int ks = 0; ks < 4; ++ks)
#pragma unroll
        for (int j = 0; j < 8; ++j) a[ks][j] = 0;
    }
  } else {
    const ushort_t* arow = A + (long long)r_log * 128 + ((l >> 4) << 3);
#pragma unroll
    for (int ks = 0; ks < 4; ++ks)
      a[ks] = *(const short8*)(arow + ks * 32);
  }

  mfma_128(a, acc, lds, l);

  long long gr0 = R0 + ((l >> 4) << 2);
  float sc[4];
#pragma unroll
  for (int r = 0; r < 4; ++r)
    sc[r] = (gr0 + r < nrows) ? (scale ? scale[gr0 + r] : 1.f) : 0.f;

  // transpose through LDS (stride 272B), then 4x16B per thread
  __syncthreads();
  int rbase = w * 16 + ((l >> 4) << 2);
#pragma unroll
  for (int c = 0; c < 8; ++c) {
    int col = c * 16 + (l & 15);
#pragma unroll
    for (int r = 0; r < 4; ++r) {
      float v = acc[c][r] * sc[r];
      *(ushort_t*)(lds + (rbase + r) * 272 + col * 2) = f2bf(v);
    }
  }
  __syncthreads();
  int row = tid >> 2, ck = tid & 3;
  long long grow = (long long)bid * 64 + row;
  if (grow < nrows) {
    const char* src = lds + row * 272 + ck * 64;
    ushort_t* dstp = outb + grow * 128 + ck * 32;
    *(short8*)(dstp)      = *(const short8*)(src);
    *(short8*)(dstp + 8)  = *(const short8*)(src + 16);
    *(short8*)(dstp + 16) = *(const short8*)(src + 32);
    *(short8*)(dstp + 24) = *(const short8*)(src + 48);
  }
}

__launch_bounds__(256, 4)
__global__ void mm_kernel(const ushort_t* __restrict__ A, const float* __restrict__ Af32,
                          int nvalid, const ushort_t* __restrict__ WT,
                          ushort_t* __restrict__ outb, int nrows,
                          const float* __restrict__ scale) {
  __shared__ __align__(16) char lds[32768];
  mm_body(A, Af32, nvalid, WT, outb, nrows, scale, blockIdx.x, lds);
}

// Fused dispatch: blocks < mmb run mm1 (x@W1 -> hb), the rest run CSR fill.
__launch_bounds__(256, 4)
__global__ void mmfill_kernel(const float* __restrict__ Af32, int nvalid,
                              const ushort_t* __restrict__ WT,
                              ushort_t* __restrict__ outb, int nrows,
                              const float* __restrict__ scale,
                              const int* __restrict__ s32, const int* __restrict__ d32,
                              long long E, int* cursor, int* csr_src, int N,
                              int mmb, int fillb) {
  __shared__ __align__(16) char lds[32768];
  if ((int)blockIdx.x < mmb) {
    mm_body(nullptr, Af32, nvalid, WT, outb, nrows, scale, blockIdx.x, lds);
  } else {
    fillp_body(s32, d32, E, cursor, csr_src, N, (int)blockIdx.x - mmb, fillb);
  }
}

// ---------------- fused decoder: d1 -> LDS tile -> d2 -> tile -> d3 -> loss --
// Per block: 64 compact rows. Intermediates never leave LDS (stride 272B tile,
// 2-way bank reads = free). Loss accumulated directly from d3 accumulators.
__launch_bounds__(256, 3)
__global__ void dec_kernel(const ushort_t* __restrict__ Z,
                           const ushort_t* __restrict__ wtD,  // D1,D2,D3 (3*16384)
                           const float* __restrict__ db1,
                           const float* __restrict__ db2,
                           const float* __restrict__ db3,
                           const float* __restrict__ x,
                           const int* __restrict__ midx,
                           const int* __restrict__ gM,
                           float* __restrict__ accum) {
  __shared__ __align__(16) char ldsW[32768];
  __shared__ __align__(16) ushort_t tile[64 * 136];  // stride 272B
  int limit = *gM;
  int bid = blockIdx.x;
  if ((long long)bid * 64 >= limit) return;

  int tid = threadIdx.x, w = tid >> 6, l = tid & 63;
  long long R0 = (long long)bid * 64 + w * 16;
  int r_log = (int)R0 + (l & 15);
  long long r_phys = (r_log < limit) ? (long long)midx[r_log] : 0;
  int rbase = w * 16 + ((l >> 4) << 2);
  int trow = w * 16 + (l & 15);
  long long gr0 = R0 + ((l >> 4) << 2);

  // ---- layer 1: A from global (gathered z rows), W = D1
  stage_w(wtD, ldsW);
  short8 a[4];
  {
    const ushort_t* arow = Z + r_phys * 128 + ((l >> 4) << 3);
#pragma unroll
    for (int ks = 0; ks < 4; ++ks) a[ks] = *(const short8*)(arow + ks * 32);
  }
  __syncthreads();
  f32x4 acc[8];
#pragma unroll
  for (int c = 0; c < 8; ++c) acc[c] = (f32x4){0.f, 0.f, 0.f, 0.f};
  mfma_128(a, acc, ldsW, l);
  // relu(acc + db1) -> tile
#pragma unroll
  for (int c = 0; c < 8; ++c) {
    int col = c * 16 + (l & 15);
    float bia = db1[col];
#pragma unroll
    for (int r = 0; r < 4; ++r)
      tile[(rbase + r) * 136 + col] = f2bf(fmaxf(acc[c][r] + bia, 0.f));
  }
  __syncthreads();

  // ---- layer 2: A from tile, W = D2
  stage_w(wtD + 16384, ldsW);
#pragma unroll
  for (int ks = 0; ks < 4; ++ks)
    a[ks] = *(const short8*)(tile + trow * 136 + ks * 32 + ((l >> 4) << 3));
  __syncthreads();
#pragma unroll
  for (int c = 0; c < 8; ++c) acc[c] = (f32x4){0.f, 0.f, 0.f, 0.f};
  mfma_128(a, acc, ldsW, l);
  __syncthreads();  // tile reads done everywhere before overwrite
#pragma unroll
  for (int c = 0; c < 8; ++c) {
    int col = c * 16 + (l & 15);
    float bia = db2[col];
#pragma unroll
    for (int r = 0; r < 4; ++r)
      tile[(rbase + r) * 136 + col] = f2bf(fmaxf(acc[c][r] + bia, 0.f));
  }
  __syncthreads();

  // ---- layer 3: A from tile, W = D3; fused masked-MSE (no stores)
  stage_w(wtD + 32768, ldsW);
#pragma unroll
  for (int ks = 0; ks < 4; ++ks)
    a[ks] = *(const short8*)(tile + trow * 136 + ks * 32 + ((l >> 4) << 3));
  __syncthreads();
#pragma unroll
  for (int c = 0; c < 8; ++c) acc[c] = (f32x4){0.f, 0.f, 0.f, 0.f};
  mfma_128(a, acc, ldsW, l);

  float local_sq = 0.f;
#pragma unroll
  for (int c = 0; c < 8; ++c) {
    int col = c * 16 + (l & 15);
    float bia = db3[col];
#pragma unroll
    for (int r = 0; r < 4; ++r) {
      if (gr0 + r < limit) {
        int orow = midx[gr0 + r];
        float d = (acc[c][r] + bia) - x[(size_t)orow * 128 + col];
        local_sq += d * d;
      }
    }
  }
  float s = local_sq;
  for (int off2 = 32; off2; off2 >>= 1) s += __shfl_down(s, off2);
  __syncthreads();  // all tile reads complete before reuse as scratch
  float* red = (float*)tile;
  if (l == 0) red[w] = s;
  __syncthreads();
  if (tid == 0) atomicAdd(accum, red[0] + red[1] + red[2] + red[3]);
}

// ---------------- GCN aggregation (wave/node; ht rows dinv-premultiplied) ----
// out[v] = relu(dv*(sum_{edges} ht[s] + ht[v]) + b); 8 gathers in flight.
__global__ void agg_kernel(const ushort_t* __restrict__ ht, const float* __restrict__ dinv,
                           const int* __restrict__ rp, const int* __restrict__ csr,
                           const float* __restrict__ bias, ushort_t* __restrict__ outb,
                           float* __restrict__ zout, int N) {
  int v = blockIdx.x * 4 + (threadIdx.x >> 6);
  if (v >= N) return;
  int l = threadIdx.x & 63;
  int off = l * 2;
  int e0 = __builtin_amdgcn_readfirstlane(rp[v]);
  int e1 = __builtin_amdgcn_readfirstlane(rp[v + 1]);

  float ax[8], ay[8];
#pragma unroll
  for (int j = 0; j < 8; ++j) { ax[j] = 0.f; ay[j] = 0.f; }

  int deg = e1 - e0;
  int nfull = deg & ~7;
  int efull = e0 + nfull;
  for (int e = e0; e < efull; e += 8) {
#pragma unroll
    for (int j = 0; j < 8; ++j) {
      int s = __builtin_amdgcn_readfirstlane(csr[e + j]);
      uint_t hv = *(const uint_t*)(ht + (size_t)s * 128 + off);
      ax[j] += u2f(hv << 16);
      ay[j] += u2f(hv & 0xffff0000u);
    }
  }
  if (efull < e1) {
#pragma unroll
    for (int j = 0; j < 8; ++j) {
      int idx = efull + j;
      int cs = __builtin_amdgcn_readfirstlane(csr[idx]);  // csr has +16 slack
      int s = (idx < e1) ? cs : N;                        // row N is all-zero
      uint_t hv = *(const uint_t*)(ht + (size_t)s * 128 + off);
      ax[j] += u2f(hv << 16);
      ay[j] += u2f(hv & 0xffff0000u);
    }
  }

  float dv = dinv[v];
  uint_t sv = *(const uint_t*)(ht + (size_t)v * 128 + off);
  float axs = ((ax[0] + ax[1]) + (ax[2] + ax[3])) + ((ax[4] + ax[5]) + (ax[6] + ax[7]));
  float ays = ((ay[0] + ay[1]) + (ay[2] + ay[3])) + ((ay[4] + ay[5]) + (ay[6] + ay[7]));
  axs += u2f(sv << 16);
  ays += u2f(sv & 0xffff0000u);
  float vx = fmaxf(dv * axs + bias[off], 0.f);
  float vy = fmaxf(dv * ays + bias[off + 1], 0.f);
  uint_t packed = (uint_t)f2bf(vx) | ((uint_t)f2bf(vy) << 16);
  *(uint_t*)(outb + (size_t)v * 128 + off) = packed;
  if (zout) {
    *(float2*)(zout + (size_t)v * 128 + off) = make_float2(vx, vy);
  }
}

__global__ void finalize_kernel(const float* accum, const int* cnt, float* out) {
  float denom = fmaxf((float)*cnt, 1.0f) * 128.0f;
  out[0] = *accum / denom;
}

// ---------------- launch ----------------
extern "C" void kernel_launch(void* const* d_in, const int* in_sizes, int n_in,
                              void* d_out, int out_size, void* d_ws, size_t ws_size,
                              hipStream_t stream) {
  const float* x  = (const float*)d_in[0];
  const void* edge = d_in[1];
  const void* mask = d_in[2];
  const float* W1 = (const float*)d_in[3];
  const float* b1 = (const float*)d_in[4];
  const float* W2 = (const float*)d_in[5];
  const float* b2 = (const float*)d_in[6];
  const float* W3 = (const float*)d_in[7];
  const float* b3 = (const float*)d_in[8];
  const float* D1 = (const float*)d_in[9];
  const float* db1 = (const float*)d_in[10];
  const float* D2 = (const float*)d_in[11];
  const float* db2 = (const float*)d_in[12];
  const float* D3 = (const float*)d_in[13];
  const float* db3 = (const float*)d_in[14];

  int N = in_sizes[0] / DD;
  long long E = in_sizes[1] / 2;
  long long Npad = ((long long)N + 63) & ~63LL;

  char* ws = (char*)d_ws;
  size_t p = 0;
  auto alloc = [&](size_t bytes) {
    size_t o = p;
    p = (p + bytes + 255) & ~(size_t)255;
    return o;
  };
  int* flags   = (int*)(ws + alloc(8));
  float* accum = (float*)(ws + alloc(4));
  int* mcnt    = (int*)(ws + alloc(4));
  int* deg     = (int*)(ws + alloc(sizeof(int) * N));
  float* dinv  = (float*)(ws + alloc(sizeof(float) * Npad));
  int* row_ptr = (int*)(ws + alloc(sizeof(int) * (N + 1)));
  int* cursor  = (int*)(ws + alloc(sizeof(int) * N));
  int* bsums   = (int*)(ws + alloc(sizeof(int) * 1024));
  int* midx    = (int*)(ws + alloc(sizeof(int) * N));
  int* s32     = (int*)(ws + alloc(sizeof(int) * E));
  int* d32     = (int*)(ws + alloc(sizeof(int) * E));
  int* csr     = (int*)(ws + alloc(sizeof(int) * (E + 16)));
  ushort_t* wt = (ushort_t*)(ws + alloc(sizeof(ushort_t) * 6 * 128 * 128));
  ushort_t* hb = (ushort_t*)(ws + alloc(sizeof(ushort_t) * (size_t)Npad * DD));
  ushort_t* gb = (ushort_t*)(ws + alloc(sizeof(ushort_t) * (size_t)Npad * DD));

  hipMemsetAsync(deg, 0, sizeof(int) * N, stream);
  hipMemsetAsync(accum, 0, 4, stream);
  hipMemsetAsync(mcnt, 0, 4, stream);
  // zero pad rows (N..Npad): row N is the agg-tail zero gather target.
  size_t padoff = (size_t)N * DD, padbytes = (size_t)(Npad - N) * DD * sizeof(ushort_t);
  hipMemsetAsync(hb + padoff, 0, padbytes, stream);
  hipMemsetAsync(gb + padoff, 0, padbytes, stream);

  // graph prep
  detect_kernel<<<1, 256, 0, stream>>>(edge, mask, E, N, flags);
  cvt_kernel<<<1024, 256, 0, stream>>>(edge, E, s32, d32, deg, flags);
  dinv_kernel<<<(int)((Npad + 255) / 256), 256, 0, stream>>>(deg, dinv, N, (int)Npad);
  int nb = (N + 1023) / 1024;
  scan1_kernel<<<nb, 1024, 0, stream>>>(deg, row_ptr, bsums, N);
  scan2_kernel<<<1, 1, 0, stream>>>(bsums, nb, row_ptr, N);
  scan3_kernel<<<nb, 1024, 0, stream>>>(row_ptr, bsums, cursor, N);
  compact_kernel<<<(N + 255) / 256, 256, 0, stream>>>(mask, flags, N, mcnt, midx);

  // weight prep (before fused mm1)
  WPtrs wp;
  wp.w[0] = W1; wp.w[1] = W2; wp.w[2] = W3;
  wp.w[3] = D1; wp.w[4] = D2; wp.w[5] = D3;
  transw_kernel<<<6, 256, 0, stream>>>(wp, wt);

  float* zout = (float*)d_out + 1;
  int mmb = (int)(Npad / 64);
  int aggb = (N + 3) / 4;
  int fillb = 4096;

  // fused: mm1 (x@W1 -> hb, dinv-scaled) concurrent with CSR fill
  mmfill_kernel<<<mmb + fillb, 256, 0, stream>>>(x, N, wt + 0 * 16384, hb,
                                                 (int)Npad, dinv, s32, d32, E,
                                                 cursor, csr, N, mmb, fillb);

  // encoder (mm stores ht = dinv * (A@W) in bf16)
  agg_kernel<<<aggb, 256, 0, stream>>>(hb, dinv, row_ptr, csr, b1, gb, nullptr, N);
  mm_kernel<<<mmb, 256, 0, stream>>>(gb, nullptr, 0, wt + 1 * 16384, hb,
                                     (int)Npad, dinv);
  agg_kernel<<<aggb, 256, 0, stream>>>(hb, dinv, row_ptr, csr, b2, gb, nullptr, N);
  mm_kernel<<<mmb, 256, 0, stream>>>(gb, nullptr, 0, wt + 2 * 16384, hb,
                                     (int)Npad, dinv);
  agg_kernel<<<aggb, 256, 0, stream>>>(hb, dinv, row_ptr, csr, b3, gb, zout, N);

  // fused decoder over compact masked rows (no global stores; loss direct)
  dec_kernel<<<mmb, 256, 0, stream>>>(gb, wt + 3 * 16384, db1, db2, db3,
                                      x, midx, mcnt, accum);

  finalize_kernel<<<1, 1, 0, stream>>>(accum, mcnt, (float*)d_out);
}